// Round 2
// baseline (6177.914 us; speedup 1.0000x reference)
//
#include <hip/hip_runtime.h>
#include <hip/hip_bf16.h>
#include <math.h>

#define DEV __device__ __forceinline__

typedef __attribute__((ext_vector_type(8))) short short8;
typedef __attribute__((ext_vector_type(4))) float f32x4;

static constexpr int Bsz  = 1024;
static constexpr int T    = 100;
static constexpr int TM1  = 99;
static constexpr int IN   = 64;
static constexpr int H    = 512;
static constexpr int OUTD = 64;
static constexpr int H2   = 1024;
static constexpr int BT   = Bsz * T;        // 102400
static constexpr int NCHUNK = 8;
static constexpr int CROWS  = BT / NCHUNK;  // 12800

DEV unsigned short f2bf(float f){
  unsigned int u = __float_as_uint(f);
  u += 0x7fffu + ((u >> 16) & 1u);          // round-to-nearest-even
  return (unsigned short)(u >> 16);
}
DEV float tanh_fast(float x){
  x = fminf(fmaxf(x, -15.f), 15.f);
  float e = __expf(2.f * x);
  return (e - 1.f) / (e + 1.f);
}

// ---------------- weight prep: bf16 transposed [N][K] panels ----------------
__global__ __launch_bounds__(256) void k_prep(const float* __restrict__ Wf1, const float* __restrict__ Wg1,
                                              const float* __restrict__ Wf2, const float* __restrict__ Wg2,
                                              const float* __restrict__ Wl1, const float* __restrict__ Wl2,
                                              unsigned short* __restrict__ W1T, unsigned short* __restrict__ W2T,
                                              unsigned short* __restrict__ Wl1T, unsigned short* __restrict__ Wl2T){
  __shared__ float tl[32][33];
  const float* src; unsigned short* dst; int N;
  switch (blockIdx.z){
    case 0: src = Wf1; dst = W1T;             N = 512; break;
    case 1: src = Wg1; dst = W1T + 512*512;   N = 512; break;
    case 2: src = Wf2; dst = W2T;             N = 512; break;
    case 3: src = Wg2; dst = W2T + 512*512;   N = 512; break;
    case 4: src = Wl1; dst = Wl1T;            N = 512; break;
    default: src = Wl2; dst = Wl2T;           N = 64;  break;
  }
  int k0 = blockIdx.x*32, n0 = blockIdx.y*32;
  if (n0 >= N) return;                        // block-uniform
  int tx = threadIdx.x, ty = threadIdx.y;     // block (32,8)
  #pragma unroll
  for (int r = 0; r < 4; r++) tl[ty + r*8][tx] = src[(size_t)(k0 + ty + r*8) * N + n0 + tx];
  __syncthreads();
  #pragma unroll
  for (int r = 0; r < 4; r++) dst[(size_t)(n0 + ty + r*8) * 512 + k0 + tx] = f2bf(tl[tx][ty + r*8]);
}

// ---------------- persistent scan: one block = 16 batch rows, all 99 steps ----------------
// block = 1024 threads = 16 waves. wave w: phase1 computes u[:, w*64..w*64+63],
// phase2 computes y-update cols w*32..w*32+31. y f32 lives in registers
// (lane-stationary), yb (bf16 A-operand) and u (bf16) live in LDS.
__global__ __launch_bounds__(1024, 4) void k_scan(
    const float* __restrict__ coeffs, const float* __restrict__ times,
    const float* __restrict__ dW,     const float* __restrict__ W_init,
    const float* __restrict__ b_init,
    const unsigned short* __restrict__ W1T, const unsigned short* __restrict__ W2T,
    const float* __restrict__ bf1, const float* __restrict__ bg1,
    const float* __restrict__ bf2, const float* __restrict__ bg2,
    float* __restrict__ z){
  __shared__ __align__(16) unsigned short yb[16][520];   // +16B pad: rows land 4 banks apart
  __shared__ __align__(16) unsigned short u [16][1032];
  __shared__ float x0s[16][64];

  const int tid = threadIdx.x, lane = tid & 63, w = tid >> 6;
  const int fr = lane & 15, fq = lane >> 4;
  const int m0 = blockIdx.x * 16;
  const int c0 = w * 32;

  // ---- init: stage x0, compute y0 = x0 @ W_init + b_init for this lane's 8 elements
  { int r = tid >> 6, k = tid & 63;
    x0s[r][k] = coeffs[(size_t)(m0 + r) * (TM1 * 4 * IN) + k]; }
  __syncthreads();

  float yreg[2][4];                            // [sub][r]: row = fq*4+r, col = c0+sub*16+fr
  #pragma unroll
  for (int sub = 0; sub < 2; sub++){
    int col = c0 + sub*16 + fr;
    #pragma unroll
    for (int r = 0; r < 4; r++){
      int row = fq*4 + r;
      float s = b_init[col];
      #pragma unroll 8
      for (int k = 0; k < IN; k++) s += x0s[row][k] * W_init[(size_t)k * H + col];
      yreg[sub][r] = s;
      yb[row][col] = f2bf(s);
      z[((size_t)(m0 + row) * T) * H + col] = s;
    }
  }
  __syncthreads();

  for (int t = 0; t < TM1; t++){
    // ---- phase 1: u = tanh(yb @ W1T^T + b1), wave w owns cols w*64..w*64+63
    f32x4 acc[4];
    #pragma unroll
    for (int s = 0; s < 4; s++) acc[s] = (f32x4){0.f,0.f,0.f,0.f};
    const unsigned short* Bp = W1T + ((size_t)(w*64 + fr)) * H + fq*8;
    #pragma unroll 4
    for (int kc = 0; kc < H; kc += 32){
      short8 a = *(const short8*)(&yb[fr][kc + fq*8]);
      #pragma unroll
      for (int s = 0; s < 4; s++){
        short8 b = *(const short8*)(Bp + (size_t)s*16*H + kc);
        acc[s] = __builtin_amdgcn_mfma_f32_16x16x32_bf16(a, b, acc[s], 0, 0, 0);
      }
    }
    const float* b1 = (w < 8) ? (bf1 + w*64) : (bg1 + w*64 - 512);
    #pragma unroll
    for (int s = 0; s < 4; s++){
      float bias = b1[s*16 + fr];
      #pragma unroll
      for (int r = 0; r < 4; r++)
        u[fq*4 + r][w*64 + s*16 + fr] = f2bf(tanh_fast(acc[s][r] + bias));
    }
    __syncthreads();

    // ---- phase 2: accf = u_f @ Wf2T^T, accg = u_g @ Wg2T^T; wave w owns y cols c0..c0+31
    float h  = times[t+1] - times[t];
    float sq = sqrtf(h);
    float dwv[2][4];
    { const float* dWp = dW + ((size_t)t * Bsz + m0) * H;
      #pragma unroll
      for (int sub = 0; sub < 2; sub++)
        #pragma unroll
        for (int r = 0; r < 4; r++)
          dwv[sub][r] = dWp[(size_t)(fq*4 + r) * H + c0 + sub*16 + fr];
    }
    float b2f[2], b2g[2];
    #pragma unroll
    for (int sub = 0; sub < 2; sub++){
      b2f[sub] = bf2[c0 + sub*16 + fr];
      b2g[sub] = bg2[c0 + sub*16 + fr];
    }
    f32x4 accf[2], accg[2];
    #pragma unroll
    for (int sub = 0; sub < 2; sub++){
      accf[sub] = (f32x4){0.f,0.f,0.f,0.f};
      accg[sub] = (f32x4){0.f,0.f,0.f,0.f};
    }
    const unsigned short* Bf = W2T + ((size_t)(c0 + fr)) * H + fq*8;
    const unsigned short* Bg = Bf + (size_t)512 * H;
    #pragma unroll 4
    for (int kc = 0; kc < H; kc += 32){
      short8 af = *(const short8*)(&u[fr][kc + fq*8]);
      short8 ag = *(const short8*)(&u[fr][512 + kc + fq*8]);
      #pragma unroll
      for (int sub = 0; sub < 2; sub++){
        short8 vbf = *(const short8*)(Bf + (size_t)sub*16*H + kc);
        short8 vbg = *(const short8*)(Bg + (size_t)sub*16*H + kc);
        accf[sub] = __builtin_amdgcn_mfma_f32_16x16x32_bf16(af, vbf, accf[sub], 0, 0, 0);
        accg[sub] = __builtin_amdgcn_mfma_f32_16x16x32_bf16(ag, vbg, accg[sub], 0, 0, 0);
      }
    }
    #pragma unroll
    for (int sub = 0; sub < 2; sub++){
      #pragma unroll
      for (int r = 0; r < 4; r++){
        int row = fq*4 + r, col = c0 + sub*16 + fr;
        float fv = accf[sub][r] + b2f[sub];
        float gv = tanh_fast(accg[sub][r] + b2g[sub]);
        float yn = yreg[sub][r] + fv*h + gv*(sq*dwv[sub][r]);
        yreg[sub][r] = yn;
        yb[row][col] = f2bf(yn);
        z[((size_t)(m0 + row) * T + (t+1)) * H + col] = yn;
      }
    }
    __syncthreads();
  }
}

// ---------------- readout helpers ----------------
DEV void stage64(const unsigned short* __restrict__ src, int stride, int row0, int col0,
                 unsigned short (*lds)[80], int tid){
  int r = tid >> 3, cg = tid & 7;
  *(uint4*)(&lds[r][cg*8])      = *(const uint4*)(src + (size_t)(row0 + r)      * stride + col0 + cg*8);
  *(uint4*)(&lds[r + 32][cg*8]) = *(const uint4*)(src + (size_t)(row0 + r + 32) * stride + col0 + cg*8);
}
DEV void stage_tanh(const float* __restrict__ src, int stride, int row0, int col0,
                    unsigned short (*lds)[80], int tid){
  int r = tid >> 4, cg = tid & 15;
  #pragma unroll
  for (int rr = 0; rr < 4; rr++){
    int row = rr*16 + r;
    float4 v = *(const float4*)(src + (size_t)(row0 + row) * stride + col0 + cg*4);
    ushort4 o;
    o.x = f2bf(tanh_fast(v.x)); o.y = f2bf(tanh_fast(v.y));
    o.z = f2bf(tanh_fast(v.z)); o.w = f2bf(tanh_fast(v.w));
    *(ushort4*)(&lds[row][cg*4]) = o;
  }
}
DEV void mfma_tile(const unsigned short (*As)[80], const unsigned short (*Bs)[80],
                   f32x4 acc[2][2], int wr, int wc, int fr, int fq){
  #pragma unroll
  for (int kk = 0; kk < 64; kk += 32){
    short8 a0 = *(const short8*)(&As[wr*32 + fr     ][kk + fq*8]);
    short8 a1 = *(const short8*)(&As[wr*32 + 16 + fr][kk + fq*8]);
    short8 b0 = *(const short8*)(&Bs[wc*32 + fr     ][kk + fq*8]);
    short8 b1 = *(const short8*)(&Bs[wc*32 + 16 + fr][kk + fq*8]);
    acc[0][0] = __builtin_amdgcn_mfma_f32_16x16x32_bf16(a0, b0, acc[0][0], 0, 0, 0);
    acc[0][1] = __builtin_amdgcn_mfma_f32_16x16x32_bf16(a0, b1, acc[0][1], 0, 0, 0);
    acc[1][0] = __builtin_amdgcn_mfma_f32_16x16x32_bf16(a1, b0, acc[1][0], 0, 0, 0);
    acc[1][1] = __builtin_amdgcn_mfma_f32_16x16x32_bf16(a1, b1, acc[1][1], 0, 0, 0);
  }
}

// ---- readout G1 (chunked): rel = relu(tanh(z_chunk) @ Wl1 + bl1)  -> bf16
__global__ __launch_bounds__(256) void k3a(const float* __restrict__ zc,
                                           const unsigned short* __restrict__ Wl1T,
                                           const float* __restrict__ bl1,
                                           unsigned short* __restrict__ rel){
  __shared__ __align__(16) unsigned short As[64][80], Bs[64][80];
  int tid = threadIdx.x, lane = tid & 63, wid = tid >> 6;
  int wr = wid >> 1, wc = wid & 1, fr = lane & 15, fq = lane >> 4;
  int m0 = blockIdx.x*64, n0 = blockIdx.y*64;
  f32x4 acc[2][2];
  #pragma unroll
  for (int m = 0; m < 2; m++)
    #pragma unroll
    for (int n = 0; n < 2; n++) acc[m][n] = (f32x4){0.f,0.f,0.f,0.f};
  for (int kc = 0; kc < H; kc += 64){
    __syncthreads();
    stage_tanh(zc,  H, m0, kc, As, tid);
    stage64(Wl1T,   H, n0, kc, Bs, tid);
    __syncthreads();
    mfma_tile(As, Bs, acc, wr, wc, fr, fq);
  }
  #pragma unroll
  for (int m = 0; m < 2; m++)
    #pragma unroll
    for (int n = 0; n < 2; n++)
      #pragma unroll
      for (int r = 0; r < 4; r++){
        int row = m0 + wr*32 + m*16 + fq*4 + r;
        int col = n0 + wc*32 + n*16 + fr;
        float v = acc[m][n][r] + bl1[col];
        rel[(size_t)row * H + col] = f2bf(fmaxf(v, 0.f));
      }
}

// ---- readout G2 (chunked): out = rel @ Wl2 + bl2  (N = 64)
__global__ __launch_bounds__(256) void k3b(const unsigned short* __restrict__ rel,
                                           const unsigned short* __restrict__ Wl2T,
                                           const float* __restrict__ bl2,
                                           float* __restrict__ outc){
  __shared__ __align__(16) unsigned short As[64][80], Bs[64][80];
  int tid = threadIdx.x, lane = tid & 63, wid = tid >> 6;
  int wr = wid >> 1, wc = wid & 1, fr = lane & 15, fq = lane >> 4;
  int m0 = blockIdx.x*64;
  f32x4 acc[2][2];
  #pragma unroll
  for (int m = 0; m < 2; m++)
    #pragma unroll
    for (int n = 0; n < 2; n++) acc[m][n] = (f32x4){0.f,0.f,0.f,0.f};
  for (int kc = 0; kc < H; kc += 64){
    __syncthreads();
    stage64(rel,  H, m0, kc, As, tid);
    stage64(Wl2T, H, 0,  kc, Bs, tid);
    __syncthreads();
    mfma_tile(As, Bs, acc, wr, wc, fr, fq);
  }
  #pragma unroll
  for (int m = 0; m < 2; m++)
    #pragma unroll
    for (int n = 0; n < 2; n++)
      #pragma unroll
      for (int r = 0; r < 4; r++){
        int row = m0 + wr*32 + m*16 + fq*4 + r;
        int col = wc*32 + n*16 + fr;           // 0..63
        outc[(size_t)row * OUTD + col] = acc[m][n][r] + bl2[col];
      }
}

extern "C" void kernel_launch(void* const* d_in, const int* in_sizes, int n_in,
                              void* d_out, int out_size, void* d_ws, size_t ws_size,
                              hipStream_t stream){
  (void)in_sizes; (void)n_in; (void)out_size; (void)ws_size;
  const float* coeffs = (const float*)d_in[0];
  const float* times  = (const float*)d_in[1];
  const float* dW     = (const float*)d_in[2];
  const float* W_init = (const float*)d_in[3];
  const float* b_init = (const float*)d_in[4];
  const float* Wf1 = (const float*)d_in[5];
  const float* bf1 = (const float*)d_in[6];
  const float* Wf2 = (const float*)d_in[7];
  const float* bf2 = (const float*)d_in[8];
  const float* Wg1 = (const float*)d_in[9];
  const float* bg1 = (const float*)d_in[10];
  const float* Wg2 = (const float*)d_in[11];
  const float* bg2 = (const float*)d_in[12];
  const float* Wl1 = (const float*)d_in[13];
  const float* bl1 = (const float*)d_in[14];
  const float* Wl2 = (const float*)d_in[15];
  const float* bl2 = (const float*)d_in[16];

  float* out = (float*)d_out;
  float* z   = out + (size_t)Bsz * T * OUTD;   // z region of d_out, (B,T,H) row-major

  char* w = (char*)d_ws;
  auto carve = [&](size_t bytes) -> void* {
    void* p = (void*)w; w += (bytes + 255) & ~(size_t)255; return p;
  };
  unsigned short* W1T  = (unsigned short*)carve((size_t)H2 * H * 2);
  unsigned short* W2T  = (unsigned short*)carve((size_t)H2 * H * 2);
  unsigned short* Wl1T = (unsigned short*)carve((size_t)H * H * 2);
  unsigned short* Wl2T = (unsigned short*)carve((size_t)OUTD * H * 2);
  unsigned short* rel  = (unsigned short*)carve((size_t)CROWS * H * 2);

  k_prep<<<dim3(16, 16, 6), dim3(32, 8), 0, stream>>>(Wf1, Wg1, Wf2, Wg2, Wl1, Wl2,
                                                      W1T, W2T, Wl1T, Wl2T);
  k_scan<<<dim3(Bsz / 16), 1024, 0, stream>>>(coeffs, times, dW, W_init, b_init,
                                              W1T, W2T, bf1, bg1, bf2, bg2, z);
  for (int c = 0; c < NCHUNK; c++){
    k3a<<<dim3(CROWS / 64, 8), 256, 0, stream>>>(z + (size_t)c * CROWS * H, Wl1T, bl1, rel);
    k3b<<<dim3(CROWS / 64, 1), 256, 0, stream>>>(rel, Wl2T, bl2, out + (size_t)c * CROWS * OUTD);
  }
}

// Round 3
// 3840.986 us; speedup vs baseline: 1.6084x; 1.6084x over previous
//
#include <hip/hip_runtime.h>
#include <hip/hip_bf16.h>
#include <math.h>

#define DEV __device__ __forceinline__

typedef __attribute__((ext_vector_type(8))) short short8;
typedef __attribute__((ext_vector_type(4))) float f32x4;

static constexpr int Bsz  = 1024;
static constexpr int T    = 100;
static constexpr int TM1  = 99;
static constexpr int IN   = 64;
static constexpr int H    = 512;
static constexpr int OUTD = 64;
static constexpr int H2   = 1024;
static constexpr int BT   = Bsz * T;        // 102400
static constexpr int NCHUNK = 8;
static constexpr int CROWS  = BT / NCHUNK;  // 12800

DEV unsigned short f2bf(float f){
  unsigned int u = __float_as_uint(f);
  u += 0x7fffu + ((u >> 16) & 1u);          // round-to-nearest-even
  return (unsigned short)(u >> 16);
}
DEV float tanh_fast(float x){
  x = fminf(fmaxf(x, -15.f), 15.f);
  float e = __expf(2.f * x);
  return (e - 1.f) / (e + 1.f);
}

// 16-block group barrier (agent-scope). Counter is monotonically increasing;
// target = epoch*16. Co-residency guaranteed: 1 block/CU, grid = 256 = #CUs.
DEV void gbar(unsigned* cnt, unsigned target){
  __syncthreads();
  if (threadIdx.x == 0){
    __threadfence();                        // release: y/u/z stores visible device-wide
    atomicAdd(cnt, 1u);
    while (__hip_atomic_load(cnt, __ATOMIC_RELAXED, __HIP_MEMORY_SCOPE_AGENT) < target)
      __builtin_amdgcn_s_sleep(1);
    __threadfence();                        // acquire: invalidate stale lines
  }
  __syncthreads();
}

// ---------------- weight prep: bf16 transposed [N][K] panels ----------------
__global__ __launch_bounds__(256) void k_prep(const float* __restrict__ Wf1, const float* __restrict__ Wg1,
                                              const float* __restrict__ Wf2, const float* __restrict__ Wg2,
                                              const float* __restrict__ Wl1, const float* __restrict__ Wl2,
                                              unsigned short* __restrict__ W1T, unsigned short* __restrict__ W2T,
                                              unsigned short* __restrict__ Wl1T, unsigned short* __restrict__ Wl2T){
  __shared__ float tl[32][33];
  const float* src; unsigned short* dst; int N;
  switch (blockIdx.z){
    case 0: src = Wf1; dst = W1T;             N = 512; break;
    case 1: src = Wg1; dst = W1T + 512*512;   N = 512; break;
    case 2: src = Wf2; dst = W2T;             N = 512; break;
    case 3: src = Wg2; dst = W2T + 512*512;   N = 512; break;
    case 4: src = Wl1; dst = Wl1T;            N = 512; break;
    default: src = Wl2; dst = Wl2T;           N = 64;  break;
  }
  int k0 = blockIdx.x*32, n0 = blockIdx.y*32;
  if (n0 >= N) return;                        // block-uniform
  int tx = threadIdx.x, ty = threadIdx.y;     // block (32,8)
  #pragma unroll
  for (int r = 0; r < 4; r++) tl[ty + r*8][tx] = src[(size_t)(k0 + ty + r*8) * N + n0 + tx];
  __syncthreads();
  #pragma unroll
  for (int r = 0; r < 4; r++) dst[(size_t)(n0 + ty + r*8) * 512 + k0 + tx] = f2bf(tl[tx][ty + r*8]);
}

__global__ void k_zero(unsigned* __restrict__ cnts){
  cnts[threadIdx.x + blockIdx.x*256] = 0u;
}

// ---------------- persistent group-synced scan ----------------
// 256 blocks x 512 threads. block b: mt = b&15 (batch rows mt*64..+64),
// ns = b>>4 (u-col slice ns*64..+64 / y-col slice ns*32..+32).
// W1/W2 slices LDS-resident (128 KB, XOR-swizzled rows). y f32 in registers.
// Per step: phase1 (u slice) -> group barrier -> phase2 (y update) -> barrier.
__global__ __launch_bounds__(512, 2) void k_scan(
    const float* __restrict__ coeffs, const float* __restrict__ times,
    const float* __restrict__ dW,     const float* __restrict__ W_init,
    const float* __restrict__ b_init,
    const unsigned short* __restrict__ W1T, const unsigned short* __restrict__ W2T,
    const float* __restrict__ bf1, const float* __restrict__ bg1,
    const float* __restrict__ bf2, const float* __restrict__ bg2,
    unsigned short* __restrict__ ybg, unsigned short* __restrict__ ubuf,
    float* __restrict__ z, unsigned* __restrict__ cnts){
  __shared__ __align__(16) unsigned char smem[147456];
  unsigned char* W1s = smem;               // [64 n][512 k] bf16, row-XOR-swizzled
  unsigned char* W2s = smem + 65536;       // rows 0..31 = Wf2T slice, 32..63 = Wg2T slice
  unsigned char* stg = smem + 131072;      // 2 x 8192 B A-tile chunks [64][64] bf16

  const int bid = blockIdx.x, mt = bid & 15, ns = bid >> 4;
  const int m0 = mt*64, n1 = ns*64, n2 = ns*32;
  const int tid = threadIdx.x, lane = tid & 63, wv = tid >> 6;
  const int fr = lane & 15, fq = lane >> 4;
  const int wm = wv >> 1, wn = wv & 1;
  unsigned* cnt = cnts + mt*64;
  unsigned ep = 0;

  // ---- stage weight slices into LDS (swizzle: 16B-unit ^= row&7) ----
  { int row = tid >> 3;
    #pragma unroll
    for (int j = 0; j < 8; j++){
      int unit = (tid & 7)*8 + j;          // 0..63 (16B units per 1024B row)
      uint4 v1 = *(const uint4*)(W1T + (size_t)(n1+row)*512 + unit*8);
      *(uint4*)(W1s + row*1024 + ((unit ^ (row & 7))<<4)) = v1;
      const unsigned short* src2 = (row < 32)
          ? (W2T + (size_t)(n2+row)*512)
          : (W2T + (size_t)512*512 + (size_t)(n2+row-32)*512);
      uint4 v2 = *(const uint4*)(src2 + unit*8);
      *(uint4*)(W2s + row*1024 + ((unit ^ (row & 7))<<4)) = v2;
    }
  }
  // ---- stage x0 rows (f32 [64][64]) into stg ----
  { int row = tid >> 3, c8 = (tid & 7)*8;
    const float* src = coeffs + (size_t)(m0+row)*(TM1*4*IN) + c8;
    *(float4*)(stg + row*256 + c8*4)      = *(const float4*)(src);
    *(float4*)(stg + row*256 + c8*4 + 16) = *(const float4*)(src + 4);
  }
  __syncthreads();

  // ---- init: y0 = x0 @ W_init + b_init (block's 64x32 slice, reg-resident) ----
  const int colL = wn*16 + fr;
  const int colG2 = n2 + colL;
  float yv[4];
  { const float* x0f = (const float*)stg;
    #pragma unroll
    for (int r = 0; r < 4; r++){
      int row = wm*16 + fq*4 + r;
      float s = b_init[colG2];
      #pragma unroll 8
      for (int k = 0; k < 64; k++) s += x0f[row*64 + k] * W_init[(size_t)k*512 + colG2];
      yv[r] = s;
      ybg[(size_t)(m0+row)*512 + colG2] = f2bf(s);
      z[((size_t)(m0+row)*T)*512 + colG2] = s;
    }
  }
  ++ep; gbar(cnt, ep*16);

  // bias preload (constant over t)
  float b1v[2];
  #pragma unroll
  for (int sub = 0; sub < 2; sub++){
    int cg = n1 + wn*32 + sub*16 + fr;
    b1v[sub] = (cg < 512) ? bf1[cg] : bg1[cg - 512];
  }
  const float b2f = bf2[colG2], b2g = bg2[colG2];

  const int srow  = wv*8 + (lane >> 3);      // staging row this lane fills
  const int sunit = lane & 7;
  const int sdst  = srow*128 + ((sunit ^ (srow & 7))<<4);
  const int arow  = wm*16 + fr;
  const int abase = arow*128;
  const int axor  = (arow & 7);

  for (int t = 0; t < TM1; t++){
    // ===== phase 1: u[m0..+64][n1..+64] = tanh(yb @ W1slice^T + b1) =====
    f32x4 acc0 = {0.f,0.f,0.f,0.f}, acc1 = {0.f,0.f,0.f,0.f};
    const unsigned short* ybrow = ybg + (size_t)(m0+srow)*512 + sunit*8;
    uint4 v = *(const uint4*)(ybrow);
    *(uint4*)(stg + sdst) = v;
    uint4 vn = *(const uint4*)(ybrow + 64);
    __syncthreads();
    #pragma unroll
    for (int c = 0; c < 8; c++){
      const unsigned char* bufc = stg + (c & 1)*8192;
      #pragma unroll
      for (int kcl = 0; kcl < 2; kcl++){
        short8 a = *(const short8*)(bufc + abase + (((kcl*4 + fq) ^ axor)<<4));
        #pragma unroll
        for (int sub = 0; sub < 2; sub++){
          int brow = wn*32 + sub*16 + fr;
          int bunit = c*8 + kcl*4 + fq;
          short8 bb = *(const short8*)(W1s + brow*1024 + ((bunit ^ (brow & 7))<<4));
          if (sub == 0) acc0 = __builtin_amdgcn_mfma_f32_16x16x32_bf16(a, bb, acc0, 0,0,0);
          else          acc1 = __builtin_amdgcn_mfma_f32_16x16x32_bf16(a, bb, acc1, 0,0,0);
        }
      }
      if (c < 7){
        __syncthreads();
        *(uint4*)(stg + ((c+1)&1)*8192 + sdst) = vn;
        if (c < 6) vn = *(const uint4*)(ybrow + (c+2)*64);
        __syncthreads();
      }
    }
    #pragma unroll
    for (int sub = 0; sub < 2; sub++){
      f32x4 av = sub ? acc1 : acc0;
      #pragma unroll
      for (int r = 0; r < 4; r++){
        int row = m0 + wm*16 + fq*4 + r;
        int col = n1 + wn*32 + sub*16 + fr;
        ubuf[(size_t)row*1024 + col] = f2bf(tanh_fast(av[r] + b1v[sub]));
      }
    }
    ++ep; gbar(cnt, ep*16);

    // ===== phase 2: y += (u_f@Wf2slice + bf2)*h + tanh(u_g@Wg2slice + bg2)*sq*dW =====
    float dwv[4];
    { const float* dWp = dW + ((size_t)t*Bsz + m0 + wm*16)*512 + colG2;
      #pragma unroll
      for (int r = 0; r < 4; r++) dwv[r] = dWp[(size_t)(fq*4 + r)*512];
    }
    float h  = times[t+1] - times[t];
    float sq = sqrtf(h);
    f32x4 accf = {0.f,0.f,0.f,0.f}, accg = {0.f,0.f,0.f,0.f};
    const unsigned short* urow = ubuf + (size_t)(m0+srow)*1024 + sunit*8;
    v = *(const uint4*)(urow);
    *(uint4*)(stg + sdst) = v;
    vn = *(const uint4*)(urow + 64);
    __syncthreads();
    #pragma unroll
    for (int c = 0; c < 16; c++){
      const unsigned char* bufc = stg + (c & 1)*8192;
      #pragma unroll
      for (int kcl = 0; kcl < 2; kcl++){
        short8 a = *(const short8*)(bufc + abase + (((kcl*4 + fq) ^ axor)<<4));
        int brow = (c < 8 ? 0 : 32) + wn*16 + fr;
        int bunit = (c & 7)*8 + kcl*4 + fq;
        short8 bb = *(const short8*)(W2s + brow*1024 + ((bunit ^ (brow & 7))<<4));
        if (c < 8) accf = __builtin_amdgcn_mfma_f32_16x16x32_bf16(a, bb, accf, 0,0,0);
        else       accg = __builtin_amdgcn_mfma_f32_16x16x32_bf16(a, bb, accg, 0,0,0);
      }
      if (c < 15){
        __syncthreads();
        *(uint4*)(stg + ((c+1)&1)*8192 + sdst) = vn;
        if (c < 14) vn = *(const uint4*)(urow + (c+2)*64);
        __syncthreads();
      }
    }
    #pragma unroll
    for (int r = 0; r < 4; r++){
      int rowG = m0 + wm*16 + fq*4 + r;
      float fv = accf[r] + b2f;
      float gv = tanh_fast(accg[r] + b2g);
      yv[r] += fv*h + gv*(sq*dwv[r]);
      ybg[(size_t)rowG*512 + colG2] = f2bf(yv[r]);
      z[((size_t)rowG*T + (t+1))*512 + colG2] = yv[r];
    }
    if (t < TM1-1){ ++ep; gbar(cnt, ep*16); }
  }
}

// ---------------- readout helpers (unchanged from R1) ----------------
DEV void stage64(const unsigned short* __restrict__ src, int stride, int row0, int col0,
                 unsigned short (*lds)[80], int tid){
  int r = tid >> 3, cg = tid & 7;
  *(uint4*)(&lds[r][cg*8])      = *(const uint4*)(src + (size_t)(row0 + r)      * stride + col0 + cg*8);
  *(uint4*)(&lds[r + 32][cg*8]) = *(const uint4*)(src + (size_t)(row0 + r + 32) * stride + col0 + cg*8);
}
DEV void stage_tanh(const float* __restrict__ src, int stride, int row0, int col0,
                    unsigned short (*lds)[80], int tid){
  int r = tid >> 4, cg = tid & 15;
  #pragma unroll
  for (int rr = 0; rr < 4; rr++){
    int row = rr*16 + r;
    float4 v = *(const float4*)(src + (size_t)(row0 + row) * stride + col0 + cg*4);
    ushort4 o;
    o.x = f2bf(tanh_fast(v.x)); o.y = f2bf(tanh_fast(v.y));
    o.z = f2bf(tanh_fast(v.z)); o.w = f2bf(tanh_fast(v.w));
    *(ushort4*)(&lds[row][cg*4]) = o;
  }
}
DEV void mfma_tile(const unsigned short (*As)[80], const unsigned short (*Bs)[80],
                   f32x4 acc[2][2], int wr, int wc, int fr, int fq){
  #pragma unroll
  for (int kk = 0; kk < 64; kk += 32){
    short8 a0 = *(const short8*)(&As[wr*32 + fr     ][kk + fq*8]);
    short8 a1 = *(const short8*)(&As[wr*32 + 16 + fr][kk + fq*8]);
    short8 b0 = *(const short8*)(&Bs[wc*32 + fr     ][kk + fq*8]);
    short8 b1 = *(const short8*)(&Bs[wc*32 + 16 + fr][kk + fq*8]);
    acc[0][0] = __builtin_amdgcn_mfma_f32_16x16x32_bf16(a0, b0, acc[0][0], 0, 0, 0);
    acc[0][1] = __builtin_amdgcn_mfma_f32_16x16x32_bf16(a0, b1, acc[0][1], 0, 0, 0);
    acc[1][0] = __builtin_amdgcn_mfma_f32_16x16x32_bf16(a1, b0, acc[1][0], 0, 0, 0);
    acc[1][1] = __builtin_amdgcn_mfma_f32_16x16x32_bf16(a1, b1, acc[1][1], 0, 0, 0);
  }
}

__global__ __launch_bounds__(256) void k3a(const float* __restrict__ zc,
                                           const unsigned short* __restrict__ Wl1T,
                                           const float* __restrict__ bl1,
                                           unsigned short* __restrict__ rel){
  __shared__ __align__(16) unsigned short As[64][80], Bs[64][80];
  int tid = threadIdx.x, lane = tid & 63, wid = tid >> 6;
  int wr = wid >> 1, wc = wid & 1, fr = lane & 15, fq = lane >> 4;
  int m0 = blockIdx.x*64, n0 = blockIdx.y*64;
  f32x4 acc[2][2];
  #pragma unroll
  for (int m = 0; m < 2; m++)
    #pragma unroll
    for (int n = 0; n < 2; n++) acc[m][n] = (f32x4){0.f,0.f,0.f,0.f};
  for (int kc = 0; kc < H; kc += 64){
    __syncthreads();
    stage_tanh(zc,  H, m0, kc, As, tid);
    stage64(Wl1T,   H, n0, kc, Bs, tid);
    __syncthreads();
    mfma_tile(As, Bs, acc, wr, wc, fr, fq);
  }
  #pragma unroll
  for (int m = 0; m < 2; m++)
    #pragma unroll
    for (int n = 0; n < 2; n++)
      #pragma unroll
      for (int r = 0; r < 4; r++){
        int row = m0 + wr*32 + m*16 + fq*4 + r;
        int col = n0 + wc*32 + n*16 + fr;
        float v = acc[m][n][r] + bl1[col];
        rel[(size_t)row * H + col] = f2bf(fmaxf(v, 0.f));
      }
}

__global__ __launch_bounds__(256) void k3b(const unsigned short* __restrict__ rel,
                                           const unsigned short* __restrict__ Wl2T,
                                           const float* __restrict__ bl2,
                                           float* __restrict__ outc){
  __shared__ __align__(16) unsigned short As[64][80], Bs[64][80];
  int tid = threadIdx.x, lane = tid & 63, wid = tid >> 6;
  int wr = wid >> 1, wc = wid & 1, fr = lane & 15, fq = lane >> 4;
  int m0 = blockIdx.x*64;
  f32x4 acc[2][2];
  #pragma unroll
  for (int m = 0; m < 2; m++)
    #pragma unroll
    for (int n = 0; n < 2; n++) acc[m][n] = (f32x4){0.f,0.f,0.f,0.f};
  for (int kc = 0; kc < H; kc += 64){
    __syncthreads();
    stage64(rel,  H, m0, kc, As, tid);
    stage64(Wl2T, H, 0,  kc, Bs, tid);
    __syncthreads();
    mfma_tile(As, Bs, acc, wr, wc, fr, fq);
  }
  #pragma unroll
  for (int m = 0; m < 2; m++)
    #pragma unroll
    for (int n = 0; n < 2; n++)
      #pragma unroll
      for (int r = 0; r < 4; r++){
        int row = m0 + wr*32 + m*16 + fq*4 + r;
        int col = wc*32 + n*16 + fr;
        outc[(size_t)row * OUTD + col] = acc[m][n][r] + bl2[col];
      }
}

extern "C" void kernel_launch(void* const* d_in, const int* in_sizes, int n_in,
                              void* d_out, int out_size, void* d_ws, size_t ws_size,
                              hipStream_t stream){
  (void)in_sizes; (void)n_in; (void)out_size; (void)ws_size;
  const float* coeffs = (const float*)d_in[0];
  const float* times  = (const float*)d_in[1];
  const float* dW     = (const float*)d_in[2];
  const float* W_init = (const float*)d_in[3];
  const float* b_init = (const float*)d_in[4];
  const float* Wf1 = (const float*)d_in[5];
  const float* bf1 = (const float*)d_in[6];
  const float* Wf2 = (const float*)d_in[7];
  const float* bf2 = (const float*)d_in[8];
  const float* Wg1 = (const float*)d_in[9];
  const float* bg1 = (const float*)d_in[10];
  const float* Wg2 = (const float*)d_in[11];
  const float* bg2 = (const float*)d_in[12];
  const float* Wl1 = (const float*)d_in[13];
  const float* bl1 = (const float*)d_in[14];
  const float* Wl2 = (const float*)d_in[15];
  const float* bl2 = (const float*)d_in[16];

  float* out = (float*)d_out;
  float* z   = out + (size_t)Bsz * T * OUTD;   // z region of d_out, (B,T,H) row-major

  char* w = (char*)d_ws;
  auto carve = [&](size_t bytes) -> void* {
    void* p = (void*)w; w += (bytes + 255) & ~(size_t)255; return p;
  };
  unsigned short* W1T  = (unsigned short*)carve((size_t)H2 * H * 2);
  unsigned short* W2T  = (unsigned short*)carve((size_t)H2 * H * 2);
  unsigned short* Wl1T = (unsigned short*)carve((size_t)H * H * 2);
  unsigned short* Wl2T = (unsigned short*)carve((size_t)OUTD * H * 2);
  unsigned short* rel  = (unsigned short*)carve((size_t)CROWS * H * 2);
  unsigned short* ybg  = (unsigned short*)carve((size_t)Bsz * H * 2);
  unsigned short* ubuf = (unsigned short*)carve((size_t)Bsz * H2 * 2);
  unsigned*       cnts = (unsigned*)carve(16 * 64 * sizeof(unsigned));

  k_zero<<<dim3(4), 256, 0, stream>>>(cnts);
  k_prep<<<dim3(16, 16, 6), dim3(32, 8), 0, stream>>>(Wf1, Wg1, Wf2, Wg2, Wl1, Wl2,
                                                      W1T, W2T, Wl1T, Wl2T);
  k_scan<<<dim3(256), 512, 0, stream>>>(coeffs, times, dW, W_init, b_init,
                                        W1T, W2T, bf1, bg1, bf2, bg2,
                                        ybg, ubuf, z, cnts);
  for (int c = 0; c < NCHUNK; c++){
    k3a<<<dim3(CROWS / 64, 8), 256, 0, stream>>>(z + (size_t)c * CROWS * H, Wl1T, bl1, rel);
    k3b<<<dim3(CROWS / 64, 1), 256, 0, stream>>>(rel, Wl2T, bl2, out + (size_t)c * CROWS * OUTD);
  }
}

// Round 4
// 3815.007 us; speedup vs baseline: 1.6194x; 1.0068x over previous
//
#include <hip/hip_runtime.h>
#include <hip/hip_bf16.h>
#include <math.h>

#define DEV __device__ __forceinline__

typedef __attribute__((ext_vector_type(8))) short short8;
typedef __attribute__((ext_vector_type(4))) float f32x4;

static constexpr int Bsz  = 1024;
static constexpr int T    = 100;
static constexpr int TM1  = 99;
static constexpr int H    = 512;
static constexpr int OUTD = 64;
static constexpr int H2   = 1024;
static constexpr int BT   = Bsz * T;        // 102400
static constexpr int NCHUNK = 8;
static constexpr int CROWS  = BT / NCHUNK;  // 12800

DEV unsigned short f2bf(float f){
  unsigned int u = __float_as_uint(f);
  u += 0x7fffu + ((u >> 16) & 1u);          // round-to-nearest-even
  return (unsigned short)(u >> 16);
}
DEV float tanh_fast(float x){
  x = fminf(fmaxf(x, -15.f), 15.f);
  float e = __expf(2.f * x);
  return (e - 1.f) / (e + 1.f);
}

// 16-block group barrier. Co-residency: 1 block/CU, grid = 256 = #CUs.
DEV void gbar(unsigned* cnt, unsigned target){
  __syncthreads();
  if (threadIdx.x == 0){
    __threadfence();                        // release (agent scope)
    atomicAdd(cnt, 1u);
    while (__hip_atomic_load(cnt, __ATOMIC_RELAXED, __HIP_MEMORY_SCOPE_AGENT) < target)
      __builtin_amdgcn_s_sleep(1);
    __threadfence();                        // acquire
  }
  __syncthreads();
}

// ---------------- weight prep: bf16 transposed [N][K] panels ----------------
__global__ __launch_bounds__(256) void k_prep(const float* __restrict__ Wf1, const float* __restrict__ Wg1,
                                              const float* __restrict__ Wf2, const float* __restrict__ Wg2,
                                              const float* __restrict__ Wl1, const float* __restrict__ Wl2,
                                              unsigned short* __restrict__ W1T, unsigned short* __restrict__ W2T,
                                              unsigned short* __restrict__ Wl1T, unsigned short* __restrict__ Wl2T){
  __shared__ float tl[32][33];
  const float* src; unsigned short* dst; int N;
  switch (blockIdx.z){
    case 0: src = Wf1; dst = W1T;             N = 512; break;
    case 1: src = Wg1; dst = W1T + 512*512;   N = 512; break;
    case 2: src = Wf2; dst = W2T;             N = 512; break;
    case 3: src = Wg2; dst = W2T + 512*512;   N = 512; break;
    case 4: src = Wl1; dst = Wl1T;            N = 512; break;
    default: src = Wl2; dst = Wl2T;           N = 64;  break;
  }
  int k0 = blockIdx.x*32, n0 = blockIdx.y*32;
  if (n0 >= N) return;
  int tx = threadIdx.x, ty = threadIdx.y;     // block (32,8)
  #pragma unroll
  for (int r = 0; r < 4; r++) tl[ty + r*8][tx] = src[(size_t)(k0 + ty + r*8) * N + n0 + tx];
  __syncthreads();
  #pragma unroll
  for (int r = 0; r < 4; r++) dst[(size_t)(n0 + ty + r*8) * 512 + k0 + tx] = f2bf(tl[tx][ty + r*8]);
}

__global__ void k_zero(unsigned* __restrict__ cnts){
  cnts[threadIdx.x] = 0u;
}

// ---------------- persistent group-synced scan, v3 ----------------
// 256 blocks x 512 thr (8 waves). block b: mt=b&15 (rows mt*64..+63), ns=b>>4
// (u-cols ns*64..+63, y-cols ns*32..+31). Weights LDS-resident in frag-major
// layout; A-fragments gathered as coalesced 1KB wave-loads from k-blocked
// global layouts ygk[16][1024][32], uk[32][1024][32]. y f32 in g-wave regs.
__global__ __launch_bounds__(512, 1) void k_scan(
    const float* __restrict__ coeffs, const float* __restrict__ times,
    const float* __restrict__ dW,     const float* __restrict__ W_init,
    const float* __restrict__ b_init,
    const unsigned short* __restrict__ W1T, const unsigned short* __restrict__ W2T,
    const float* __restrict__ bf1, const float* __restrict__ bg1,
    const float* __restrict__ bf2, const float* __restrict__ bg2,
    unsigned short* __restrict__ ygk, unsigned short* __restrict__ uk,
    float* __restrict__ z, unsigned* __restrict__ cnts){
  __shared__ __align__(16) unsigned short W1s[32768];  // 64KB frag-major (kc,cl,fq)
  __shared__ __align__(16) unsigned short W2s[32768];  // 64KB: cl<32 f-cols, >=32 g-cols
  __shared__ __align__(16) float cmb[64*68];           // 17KB combine / x0 stage

  const int bid = blockIdx.x, mt = bid & 15, ns = bid >> 4;
  const int m0 = mt*64, n1 = ns*64, n2 = ns*32;
  const int tid = threadIdx.x, lane = tid & 63, w = tid >> 6;
  const int fr = lane & 15, fq = lane >> 4;
  const int band = w & 3, rn = w >> 2;      // ph1 region; ph2: band, isg=rn
  const int isg = rn;
  unsigned* cnt = cnts + mt*16;
  unsigned ep = 0;

  // ---- stage weight slices into LDS (frag-major linear) ----
  #pragma unroll
  for (int i = 0; i < 8; i++){
    int u = i*512 + tid;                     // 0..4095
    int fqi = u & 3, cl = (u >> 2) & 63, kc = u >> 8;
    *(uint4*)(W1s + u*8) = *(const uint4*)(W1T + (size_t)(n1+cl)*512 + kc*32 + fqi*8);
    const unsigned short* s2 = (cl < 32) ? (W2T + (size_t)(n2+cl)*512)
                                         : (W2T + 262144 + (size_t)(n2+cl-32)*512);
    *(uint4*)(W2s + u*8) = *(const uint4*)(s2 + kc*32 + fqi*8);
  }
  // ---- stage x0 (64x64 f32) ----
  { int row = tid >> 3, c0 = (tid & 7)*8;
    const float* src = coeffs + (size_t)(m0+row)*(TM1*4*64) + c0;
    *(float4*)(&cmb[row*68 + c0])     = *(const float4*)src;
    *(float4*)(&cmb[row*68 + c0 + 4]) = *(const float4*)(src + 4);
  }
  __syncthreads();

  // ---- init: y0 (g-waves own y: rows band*16+fq*4+r, cols n2+sub*16+fr) ----
  float yv[2][4];
  if (isg){
    #pragma unroll
    for (int sub = 0; sub < 2; sub++){
      int c = n2 + sub*16 + fr;
      #pragma unroll
      for (int r = 0; r < 4; r++){
        int row = band*16 + fq*4 + r;
        float s = b_init[c];
        #pragma unroll 8
        for (int k = 0; k < 64; k++) s += cmb[row*68 + k] * W_init[(size_t)k*512 + c];
        yv[sub][r] = s;
        ygk[(size_t)ns*32768 + (size_t)(m0+row)*32 + sub*16 + fr] = f2bf(s);
        z[((size_t)(m0+row)*T)*512 + c] = s;
      }
    }
  }
  ++ep; gbar(cnt, ep*16);

  // bias preloads
  float b1v[2], b2v[2];
  #pragma unroll
  for (int sub = 0; sub < 2; sub++){
    int cg = n1 + rn*32 + sub*16 + fr;
    b1v[sub] = (cg < 512) ? bf1[cg] : bg1[cg - 512];
    int c2 = n2 + sub*16 + fr;
    b2v[sub] = isg ? bg2[c2] : bf2[c2];
  }

  const unsigned short* yrow = ygk + (size_t)(m0 + band*16 + fr)*32 + fq*8;
  const unsigned short* urow = uk + (size_t)isg*16*32768 + (size_t)(m0 + band*16 + fr)*32 + fq*8;
  unsigned short* ywr = ygk + (size_t)ns*32768 + (size_t)m0*32;
  unsigned short* uwr = uk + (size_t)(ns*2 + rn)*32768 + (size_t)m0*32;

  for (int t = 0; t < TM1; t++){
    // ===== phase 1: u[rows band][cols rn*32..+31 of slice] =====
    f32x4 p0 = {0.f,0.f,0.f,0.f}, p1 = {0.f,0.f,0.f,0.f};
    uint4 ap[4];
    #pragma unroll
    for (int i = 0; i < 4; i++) ap[i] = *(const uint4*)(yrow + (size_t)i*32768);
    #pragma unroll
    for (int kc = 0; kc < 16; kc++){
      short8 a = *(short8*)&ap[kc & 3];
      short8 b0 = *(const short8*)(W1s + kc*2048 + (rn*32 + fr)*32 + fq*8);
      short8 b1 = *(const short8*)(W1s + kc*2048 + (rn*32 + 16 + fr)*32 + fq*8);
      p0 = __builtin_amdgcn_mfma_f32_16x16x32_bf16(a, b0, p0, 0, 0, 0);
      p1 = __builtin_amdgcn_mfma_f32_16x16x32_bf16(a, b1, p1, 0, 0, 0);
      if (kc < 12) ap[kc & 3] = *(const uint4*)(yrow + (size_t)(kc+4)*32768);
    }
    #pragma unroll
    for (int sub = 0; sub < 2; sub++){
      f32x4 pv = sub ? p1 : p0;
      #pragma unroll
      for (int r = 0; r < 4; r++){
        int row = band*16 + fq*4 + r;
        uwr[(size_t)row*32 + sub*16 + fr] = f2bf(tanh_fast(pv[r] + b1v[sub]));
      }
    }
    ++ep; gbar(cnt, ep*16);

    // ===== phase 2: f-waves (rn=0) compute f-strip, g-waves (rn=1) g-strip =====
    float dwv[2][4];
    if (isg){
      const float* dWp = dW + (size_t)t*524288 + (size_t)(m0 + band*16)*512 + n2;
      #pragma unroll
      for (int sub = 0; sub < 2; sub++)
        #pragma unroll
        for (int r = 0; r < 4; r++)
          dwv[sub][r] = dWp[(size_t)(fq*4 + r)*512 + sub*16 + fr];
    }
    f32x4 q0 = {0.f,0.f,0.f,0.f}, q1 = {0.f,0.f,0.f,0.f};
    #pragma unroll
    for (int i = 0; i < 4; i++) ap[i] = *(const uint4*)(urow + (size_t)i*32768);
    #pragma unroll
    for (int kc = 0; kc < 16; kc++){
      short8 a = *(short8*)&ap[kc & 3];
      short8 b0 = *(const short8*)(W2s + kc*2048 + (isg*32 + fr)*32 + fq*8);
      short8 b1 = *(const short8*)(W2s + kc*2048 + (isg*32 + 16 + fr)*32 + fq*8);
      q0 = __builtin_amdgcn_mfma_f32_16x16x32_bf16(a, b0, q0, 0, 0, 0);
      q1 = __builtin_amdgcn_mfma_f32_16x16x32_bf16(a, b1, q1, 0, 0, 0);
      if (kc < 12) ap[kc & 3] = *(const uint4*)(urow + (size_t)(kc+4)*32768);
    }
    if (!isg){
      #pragma unroll
      for (int sub = 0; sub < 2; sub++){
        f32x4 qv = sub ? q1 : q0;
        #pragma unroll
        for (int r = 0; r < 4; r++)
          cmb[(band*16 + fq*4 + r)*68 + sub*16 + fr] = qv[r] + b2v[sub];
      }
    }
    __syncthreads();
    if (isg){
      float h  = times[t+1] - times[t];
      float sq = sqrtf(h);
      #pragma unroll
      for (int sub = 0; sub < 2; sub++){
        f32x4 qv = sub ? q1 : q0;
        #pragma unroll
        for (int r = 0; r < 4; r++){
          int row = band*16 + fq*4 + r;
          float fv = cmb[row*68 + sub*16 + fr];
          float gv = tanh_fast(qv[r] + b2v[sub]);
          float yn = yv[sub][r] + fv*h + gv*(sq*dwv[sub][r]);
          yv[sub][r] = yn;
          ywr[(size_t)row*32 + sub*16 + fr] = f2bf(yn);
          z[((size_t)(m0+row)*T + (t+1))*512 + n2 + sub*16 + fr] = yn;
        }
      }
    }
    if (t < TM1-1){ ++ep; gbar(cnt, ep*16); }
  }
}

// ---------------- readout (unchanged) ----------------
DEV void stage64(const unsigned short* __restrict__ src, int stride, int row0, int col0,
                 unsigned short (*lds)[80], int tid){
  int r = tid >> 3, cg = tid & 7;
  *(uint4*)(&lds[r][cg*8])      = *(const uint4*)(src + (size_t)(row0 + r)      * stride + col0 + cg*8);
  *(uint4*)(&lds[r + 32][cg*8]) = *(const uint4*)(src + (size_t)(row0 + r + 32) * stride + col0 + cg*8);
}
DEV void stage_tanh(const float* __restrict__ src, int stride, int row0, int col0,
                    unsigned short (*lds)[80], int tid){
  int r = tid >> 4, cg = tid & 15;
  #pragma unroll
  for (int rr = 0; rr < 4; rr++){
    int row = rr*16 + r;
    float4 v = *(const float4*)(src + (size_t)(row0 + row) * stride + col0 + cg*4);
    ushort4 o;
    o.x = f2bf(tanh_fast(v.x)); o.y = f2bf(tanh_fast(v.y));
    o.z = f2bf(tanh_fast(v.z)); o.w = f2bf(tanh_fast(v.w));
    *(ushort4*)(&lds[row][cg*4]) = o;
  }
}
DEV void mfma_tile(const unsigned short (*As)[80], const unsigned short (*Bs)[80],
                   f32x4 acc[2][2], int wr, int wc, int fr, int fq){
  #pragma unroll
  for (int kk = 0; kk < 64; kk += 32){
    short8 a0 = *(const short8*)(&As[wr*32 + fr     ][kk + fq*8]);
    short8 a1 = *(const short8*)(&As[wr*32 + 16 + fr][kk + fq*8]);
    short8 b0 = *(const short8*)(&Bs[wc*32 + fr     ][kk + fq*8]);
    short8 b1 = *(const short8*)(&Bs[wc*32 + 16 + fr][kk + fq*8]);
    acc[0][0] = __builtin_amdgcn_mfma_f32_16x16x32_bf16(a0, b0, acc[0][0], 0, 0, 0);
    acc[0][1] = __builtin_amdgcn_mfma_f32_16x16x32_bf16(a0, b1, acc[0][1], 0, 0, 0);
    acc[1][0] = __builtin_amdgcn_mfma_f32_16x16x32_bf16(a1, b0, acc[1][0], 0, 0, 0);
    acc[1][1] = __builtin_amdgcn_mfma_f32_16x16x32_bf16(a1, b1, acc[1][1], 0, 0, 0);
  }
}

__global__ __launch_bounds__(256) void k3a(const float* __restrict__ zc,
                                           const unsigned short* __restrict__ Wl1T,
                                           const float* __restrict__ bl1,
                                           unsigned short* __restrict__ rel){
  __shared__ __align__(16) unsigned short As[64][80], Bs[64][80];
  int tid = threadIdx.x, lane = tid & 63, wid = tid >> 6;
  int wr = wid >> 1, wc = wid & 1, fr = lane & 15, fq = lane >> 4;
  int m0 = blockIdx.x*64, n0 = blockIdx.y*64;
  f32x4 acc[2][2];
  #pragma unroll
  for (int m = 0; m < 2; m++)
    #pragma unroll
    for (int n = 0; n < 2; n++) acc[m][n] = (f32x4){0.f,0.f,0.f,0.f};
  for (int kc = 0; kc < H; kc += 64){
    __syncthreads();
    stage_tanh(zc,  H, m0, kc, As, tid);
    stage64(Wl1T,   H, n0, kc, Bs, tid);
    __syncthreads();
    mfma_tile(As, Bs, acc, wr, wc, fr, fq);
  }
  #pragma unroll
  for (int m = 0; m < 2; m++)
    #pragma unroll
    for (int n = 0; n < 2; n++)
      #pragma unroll
      for (int r = 0; r < 4; r++){
        int row = m0 + wr*32 + m*16 + fq*4 + r;
        int col = n0 + wc*32 + n*16 + fr;
        float v = acc[m][n][r] + bl1[col];
        rel[(size_t)row * H + col] = f2bf(fmaxf(v, 0.f));
      }
}

__global__ __launch_bounds__(256) void k3b(const unsigned short* __restrict__ rel,
                                           const unsigned short* __restrict__ Wl2T,
                                           const float* __restrict__ bl2,
                                           float* __restrict__ outc){
  __shared__ __align__(16) unsigned short As[64][80], Bs[64][80];
  int tid = threadIdx.x, lane = tid & 63, wid = tid >> 6;
  int wr = wid >> 1, wc = wid & 1, fr = lane & 15, fq = lane >> 4;
  int m0 = blockIdx.x*64;
  f32x4 acc[2][2];
  #pragma unroll
  for (int m = 0; m < 2; m++)
    #pragma unroll
    for (int n = 0; n < 2; n++) acc[m][n] = (f32x4){0.f,0.f,0.f,0.f};
  for (int kc = 0; kc < H; kc += 64){
    __syncthreads();
    stage64(rel,  H, m0, kc, As, tid);
    stage64(Wl2T, H, 0,  kc, Bs, tid);
    __syncthreads();
    mfma_tile(As, Bs, acc, wr, wc, fr, fq);
  }
  #pragma unroll
  for (int m = 0; m < 2; m++)
    #pragma unroll
    for (int n = 0; n < 2; n++)
      #pragma unroll
      for (int r = 0; r < 4; r++){
        int row = m0 + wr*32 + m*16 + fq*4 + r;
        int col = wc*32 + n*16 + fr;
        outc[(size_t)row * OUTD + col] = acc[m][n][r] + bl2[col];
      }
}

extern "C" void kernel_launch(void* const* d_in, const int* in_sizes, int n_in,
                              void* d_out, int out_size, void* d_ws, size_t ws_size,
                              hipStream_t stream){
  (void)in_sizes; (void)n_in; (void)out_size; (void)ws_size;
  const float* coeffs = (const float*)d_in[0];
  const float* times  = (const float*)d_in[1];
  const float* dW     = (const float*)d_in[2];
  const float* W_init = (const float*)d_in[3];
  const float* b_init = (const float*)d_in[4];
  const float* Wf1 = (const float*)d_in[5];
  const float* bf1 = (const float*)d_in[6];
  const float* Wf2 = (const float*)d_in[7];
  const float* bf2 = (const float*)d_in[8];
  const float* Wg1 = (const float*)d_in[9];
  const float* bg1 = (const float*)d_in[10];
  const float* Wg2 = (const float*)d_in[11];
  const float* bg2 = (const float*)d_in[12];
  const float* Wl1 = (const float*)d_in[13];
  const float* bl1 = (const float*)d_in[14];
  const float* Wl2 = (const float*)d_in[15];
  const float* bl2 = (const float*)d_in[16];

  float* out = (float*)d_out;
  float* z   = out + (size_t)Bsz * T * OUTD;   // z region of d_out, (B,T,H)

  char* w = (char*)d_ws;
  auto carve = [&](size_t bytes) -> void* {
    void* p = (void*)w; w += (bytes + 255) & ~(size_t)255; return p;
  };
  unsigned short* W1T  = (unsigned short*)carve((size_t)H2 * H * 2);
  unsigned short* W2T  = (unsigned short*)carve((size_t)H2 * H * 2);
  unsigned short* Wl1T = (unsigned short*)carve((size_t)H * H * 2);
  unsigned short* Wl2T = (unsigned short*)carve((size_t)OUTD * H * 2);
  unsigned short* rel  = (unsigned short*)carve((size_t)CROWS * H * 2);
  unsigned short* ygk  = (unsigned short*)carve((size_t)Bsz * H * 2);   // [16][1024][32]
  unsigned short* uk   = (unsigned short*)carve((size_t)Bsz * H2 * 2);  // [32][1024][32]
  unsigned*       cnts = (unsigned*)carve(256 * sizeof(unsigned));

  k_zero<<<dim3(1), 256, 0, stream>>>(cnts);
  k_prep<<<dim3(16, 16, 6), dim3(32, 8), 0, stream>>>(Wf1, Wg1, Wf2, Wg2, Wl1, Wl2,
                                                      W1T, W2T, Wl1T, Wl2T);
  k_scan<<<dim3(256), 512, 0, stream>>>(coeffs, times, dW, W_init, b_init,
                                        W1T, W2T, bf1, bg1, bf2, bg2,
                                        ygk, uk, z, cnts);
  for (int c = 0; c < NCHUNK; c++){
    k3a<<<dim3(CROWS / 64, 8), 256, 0, stream>>>(z + (size_t)c * CROWS * H, Wl1T, bl1, rel);
    k3b<<<dim3(CROWS / 64, 1), 256, 0, stream>>>(rel, Wl2T, bl2, out + (size_t)c * CROWS * OUTD);
  }
}

// Round 6
// 1181.547 us; speedup vs baseline: 5.2287x; 3.2288x over previous
//
#include <hip/hip_runtime.h>
#include <hip/hip_bf16.h>
#include <math.h>

#define DEV __device__ __forceinline__

typedef __attribute__((ext_vector_type(8))) short short8;
typedef __attribute__((ext_vector_type(4))) float f32x4;
typedef __attribute__((ext_vector_type(4))) unsigned int u32x4;

static constexpr int Bsz  = 1024;
static constexpr int T    = 100;
static constexpr int TM1  = 99;
static constexpr int H    = 512;
static constexpr int OUTD = 64;
static constexpr int H2   = 1024;
static constexpr int BT   = Bsz * T;        // 102400
static constexpr int NCHUNK = 8;
static constexpr int CROWS  = BT / NCHUNK;  // 12800

DEV unsigned short f2bf(float f){
  unsigned int u = __float_as_uint(f);
  u += 0x7fffu + ((u >> 16) & 1u);          // round-to-nearest-even
  return (unsigned short)(u >> 16);
}
DEV unsigned pack2(float lo, float hi){
  return (unsigned)f2bf(lo) | ((unsigned)f2bf(hi) << 16);
}
DEV float tanh_fast(float x){
  x = fminf(fmaxf(x, -15.f), 15.f);
  float e = __expf(2.f * x);
  return (e - 1.f) / (e + 1.f);
}

// coherent (agent-scope, L3-backed) data path — no cache maintenance needed
#define AISSUE(dst, p) asm volatile("global_load_dwordx4 %0, %1, off sc0 sc1" : "=&v"(dst) : "v"(p) : "memory")
#define PLOAD(dst, p)  asm volatile("global_load_dword %0, %1, off"          : "=&v"(dst) : "v"(p) : "memory")
#define SC_STORE(p, v) asm volatile("global_store_dword %0, %1, off sc0 sc1" :: "v"(p), "v"(v) : "memory")
#define VWAIT(n)       asm volatile("s_waitcnt vmcnt(" #n ")" ::: "memory"); __builtin_amdgcn_sched_barrier(0)
#define VDRAIN()       asm volatile("s_waitcnt vmcnt(0)" ::: "memory")

// fence-free 16-block group barrier (data travels via sc0sc1 -> L3; flag via agent atomics)
DEV void gbar(unsigned* cnt, unsigned target){
  VDRAIN();
  __syncthreads();
  if (threadIdx.x == 0){
    __hip_atomic_fetch_add(cnt, 1u, __ATOMIC_RELAXED, __HIP_MEMORY_SCOPE_AGENT);
    while (__hip_atomic_load(cnt, __ATOMIC_RELAXED, __HIP_MEMORY_SCOPE_AGENT) < target)
      __builtin_amdgcn_s_sleep(2);
  }
  __syncthreads();
}

// ---------------- weight prep: bf16 transposed [N][K] panels ----------------
// For W1T/W2T (scan weights) the K dim is sigma-permuted within each 32-block:
// stored position p holds logical k = (p&1)*16 + (p>>1); activations y/u are
// stored with the same permutation, so MFMA dot products are unchanged.
__global__ __launch_bounds__(256) void k_prep(const float* __restrict__ Wf1, const float* __restrict__ Wg1,
                                              const float* __restrict__ Wf2, const float* __restrict__ Wg2,
                                              const float* __restrict__ Wl1, const float* __restrict__ Wl2,
                                              unsigned short* __restrict__ W1T, unsigned short* __restrict__ W2T,
                                              unsigned short* __restrict__ Wl1T, unsigned short* __restrict__ Wl2T){
  __shared__ float tl[32][33];
  const float* src; unsigned short* dst; int N;
  bool perm = (blockIdx.z < 4);
  switch (blockIdx.z){
    case 0: src = Wf1; dst = W1T;             N = 512; break;
    case 1: src = Wg1; dst = W1T + 512*512;   N = 512; break;
    case 2: src = Wf2; dst = W2T;             N = 512; break;
    case 3: src = Wg2; dst = W2T + 512*512;   N = 512; break;
    case 4: src = Wl1; dst = Wl1T;            N = 512; break;
    default: src = Wl2; dst = Wl2T;           N = 64;  break;
  }
  int k0 = blockIdx.x*32, n0 = blockIdx.y*32;
  if (n0 >= N) return;
  int tx = threadIdx.x, ty = threadIdx.y;     // block (32,8)
  #pragma unroll
  for (int r = 0; r < 4; r++) tl[ty + r*8][tx] = src[(size_t)(k0 + ty + r*8) * N + n0 + tx];
  __syncthreads();
  int kpos = perm ? (k0 + ((tx & 15)*2 + (tx >> 4))) : (k0 + tx);
  #pragma unroll
  for (int r = 0; r < 4; r++) dst[(size_t)(n0 + ty + r*8) * 512 + kpos] = f2bf(tl[tx][ty + r*8]);
}

__global__ void k_zero(unsigned* __restrict__ cnts){
  cnts[threadIdx.x + blockIdx.x*256] = 0u;
}

// one K-step of the MFMA pipeline (4-deep counted prefetch)
#define KSTEP(K, W, AB, WB, A0, A1) \
  VWAIT(W); \
  { short8 a_  = *(short8*)&ap[(K)&3]; \
    short8 b0_ = *(const short8*)((WB) + (K)*4096 + fr*64 + fq*16); \
    short8 b1_ = *(const short8*)((WB) + (K)*4096 + 1024 + fr*64 + fq*16); \
    A0 = __builtin_amdgcn_mfma_f32_16x16x32_bf16(a_, b0_, A0, 0,0,0); \
    A1 = __builtin_amdgcn_mfma_f32_16x16x32_bf16(a_, b1_, A1, 0,0,0); } \
  if ((K) < 12) { AISSUE(ap[(K)&3], (AB) + (size_t)((K)+4)*65536); }

#define RUN16(AB, WB, A0, A1) \
  AISSUE(ap[0], (AB)); AISSUE(ap[1], (AB)+65536); \
  AISSUE(ap[2], (AB)+131072); AISSUE(ap[3], (AB)+196608); \
  KSTEP( 0,3,AB,WB,A0,A1) KSTEP( 1,3,AB,WB,A0,A1) KSTEP( 2,3,AB,WB,A0,A1) KSTEP( 3,3,AB,WB,A0,A1) \
  KSTEP( 4,3,AB,WB,A0,A1) KSTEP( 5,3,AB,WB,A0,A1) KSTEP( 6,3,AB,WB,A0,A1) KSTEP( 7,3,AB,WB,A0,A1) \
  KSTEP( 8,3,AB,WB,A0,A1) KSTEP( 9,3,AB,WB,A0,A1) KSTEP(10,3,AB,WB,A0,A1) KSTEP(11,3,AB,WB,A0,A1) \
  KSTEP(12,3,AB,WB,A0,A1) KSTEP(13,2,AB,WB,A0,A1) KSTEP(14,1,AB,WB,A0,A1) KSTEP(15,0,AB,WB,A0,A1)

// ---------------- persistent group-synced scan, v4 (fence-free) ----------------
// 256 blocks x 512 thr (8 waves). block b: mt=b&15 (rows mt*64..+63), ns=b>>4
// (u-cols ns*64..+63, y-cols ns*32..+31). Weights LDS-resident frag-major
// [kc][col][fq]; A-operands read as 1KB/wave sc0sc1 dwordx4 loads from
// k-blocked, k-permuted global layouts ygk[16][1024][32], uk[32][1024][32].
__global__ __launch_bounds__(512, 1) void k_scan(
    const float* __restrict__ coeffs, const float* __restrict__ times,
    const float* __restrict__ dW,     const float* __restrict__ W_init,
    const float* __restrict__ b_init,
    const unsigned short* __restrict__ W1T, const unsigned short* __restrict__ W2T,
    const float* __restrict__ bf1, const float* __restrict__ bg1,
    const float* __restrict__ bf2, const float* __restrict__ bg2,
    unsigned short* __restrict__ ygk, unsigned short* __restrict__ uk,
    float* __restrict__ z, unsigned* __restrict__ cnts){
  __shared__ __align__(16) unsigned char W1s[65536];   // [16 kc][64 col][4 fq] x16B
  __shared__ __align__(16) unsigned char W2s[65536];   // col<32: f-slice, col>=32: g-slice
  __shared__ __align__(16) float cmb[64*68];           // f-result exchange / x0 stage
  __shared__ float tms[104];

  const int bid = blockIdx.x, mt = bid & 15, ns = bid >> 4;
  const int m0 = mt*64, n1 = ns*64, n2 = ns*32;
  const int tid = threadIdx.x, lane = tid & 63, w = tid >> 6;
  const int fr = lane & 15, fq = lane >> 4;
  const int band = w & 3, isg = w >> 2;     // phase1: (band, rn=isg); phase2: (band, f/g)
  unsigned* cnt = cnts + mt*32;
  unsigned ep = 0;

  // ---- stage weight slices into LDS (linear position copy -> frag-major) ----
  #pragma unroll
  for (int i = 0; i < 8; i++){
    int u = i*512 + tid;                     // unit = (kc*64+cl)*4+fqi
    int fqi = u & 3, cl = (u >> 2) & 63, kc = u >> 8;
    *(uint4*)(W1s + (size_t)u*16) = *(const uint4*)(W1T + (size_t)(n1+cl)*512 + kc*32 + fqi*8);
    const unsigned short* s2 = (cl < 32) ? (W2T + (size_t)(n2+cl)*512)
                                         : (W2T + (size_t)262144 + (size_t)(n2+cl-32)*512);
    *(uint4*)(W2s + (size_t)u*16) = *(const uint4*)(s2 + kc*32 + fqi*8);
  }
  if (tid < 100) tms[tid] = times[tid];
  // ---- stage x0 (64x64 f32) ----
  { int row = tid >> 3, c0 = (tid & 7)*8;
    const float* src = coeffs + (size_t)(m0+row)*(TM1*4*64) + c0;
    *(float4*)(&cmb[row*68 + c0])     = *(const float4*)src;
    *(float4*)(&cmb[row*68 + c0 + 4]) = *(const float4*)(src + 4);
  }
  __syncthreads();

  // per-lane pointers
  char* ygkb = (char*)ygk;
  char* ukb  = (char*)uk;
  const char* abase1 = ygkb + ((size_t)(m0 + band*16 + fr))*64 + fq*16;
  const char* abase2 = ukb + (size_t)isg*1048576 + ((size_t)(m0 + band*16 + fr))*64 + fq*16;
  char* ust = ukb  + ((size_t)((ns*2+isg)*1024 + m0 + band*16 + fq*4))*64 + fr*4;
  char* yst = ygkb + ((size_t)(ns*1024        + m0 + band*16 + fq*4))*64 + fr*4;
  const unsigned char* Wb1 = W1s + isg*2048;
  const unsigned char* Wb2 = W2s + isg*2048;
  const float* dwb = dW + (size_t)(m0 + band*16 + fq*4)*512 + n2 + fr;
  float*       zb  = z  + ((size_t)(m0 + band*16 + fq*4)*T)*512 + n2 + fr;

  // ---- init: y0 = x0 @ W_init + b_init (g-waves own y slice) ----
  float yv[2][4];
  if (isg){
    #pragma unroll
    for (int r = 0; r < 4; r++){
      int row = band*16 + fq*4 + r;
      float s0 = b_init[n2 + fr], s1 = b_init[n2 + 16 + fr];
      #pragma unroll 8
      for (int k = 0; k < 64; k++){
        float xv = cmb[row*68 + k];
        s0 += xv * W_init[(size_t)k*512 + n2 + fr];
        s1 += xv * W_init[(size_t)k*512 + n2 + 16 + fr];
      }
      yv[0][r] = s0; yv[1][r] = s1;
      unsigned pv = pack2(s0, s1);
      SC_STORE(yst + r*64, pv);
      zb[(size_t)r*T*512]          = s0;       // z[.., t=0, n2+fr]
      zb[(size_t)r*T*512 + 16]     = s1;       // z[.., t=0, n2+16+fr]
    }
  }
  ++ep; gbar(cnt, ep*16);

  // bias preloads
  const float b1v0 = ((n1 + isg*32 +      fr) < 512) ? bf1[n1 + isg*32 + fr]      : bg1[n1 + isg*32 + fr - 512];
  const float b1v1 = ((n1 + isg*32 + 16 + fr) < 512) ? bf1[n1 + isg*32 + 16 + fr] : bg1[n1 + isg*32 + 16 + fr - 512];
  const float b2v0 = isg ? bg2[n2 + fr]      : bf2[n2 + fr];
  const float b2v1 = isg ? bg2[n2 + 16 + fr] : bf2[n2 + 16 + fr];

  for (int t = 0; t < TM1; t++){
    // ===== phase 1: u[m0..+63][n1 + isg*32 + {fr, 16+fr}] = tanh(y @ W1 + b1) =====
    {
      f32x4 p0 = {0.f,0.f,0.f,0.f}, p1 = {0.f,0.f,0.f,0.f};
      u32x4 ap[4];
      RUN16(abase1, Wb1, p0, p1);
      #pragma unroll
      for (int r = 0; r < 4; r++){
        unsigned pv = pack2(tanh_fast(p0[r] + b1v0), tanh_fast(p1[r] + b1v1));
        SC_STORE(ust + r*64, pv);
      }
    }
    ++ep; gbar(cnt, ep*16);

    // ===== phase 2: f-waves u_f@Wf2, g-waves u_g@Wg2 + combine + y update =====
    {
      float h  = tms[t+1] - tms[t];
      float sq = sqrtf(h);
      float dv[8];
      if (isg){
        const char* dp = (const char*)(dwb + (size_t)t*524288);
        PLOAD(dv[0], dp + 0);    PLOAD(dv[1], dp + 64);
        PLOAD(dv[2], dp + 2048); PLOAD(dv[3], dp + 2048+64);
        PLOAD(dv[4], dp + 4096); PLOAD(dv[5], dp + 4096+64);
        PLOAD(dv[6], dp + 6144); PLOAD(dv[7], dp + 6144+64);
      }
      f32x4 q0 = {0.f,0.f,0.f,0.f}, q1 = {0.f,0.f,0.f,0.f};
      u32x4 ap[4];
      RUN16(abase2, Wb2, q0, q1);
      if (!isg){
        #pragma unroll
        for (int r = 0; r < 4; r++){
          int row = band*16 + fq*4 + r;
          cmb[row*68 + fr]      = q0[r] + b2v0;
          cmb[row*68 + 16 + fr] = q1[r] + b2v1;
        }
      }
      __syncthreads();
      if (isg){
        #pragma unroll
        for (int r = 0; r < 4; r++){
          int row = band*16 + fq*4 + r;
          float f0 = cmb[row*68 + fr],      f1 = cmb[row*68 + 16 + fr];
          float g0 = tanh_fast(q0[r] + b2v0), g1 = tanh_fast(q1[r] + b2v1);
          float y0n = yv[0][r] + f0*h + g0*(sq*dv[r*2]);
          float y1n = yv[1][r] + f1*h + g1*(sq*dv[r*2+1]);
          yv[0][r] = y0n; yv[1][r] = y1n;
          unsigned pv = pack2(y0n, y1n);
          SC_STORE(yst + r*64, pv);
          zb[(size_t)r*T*512 + (size_t)(t+1)*512]      = y0n;
          zb[(size_t)r*T*512 + (size_t)(t+1)*512 + 16] = y1n;
        }
      }
    }
    if (t < TM1-1){ ++ep; gbar(cnt, ep*16); }
  }
}

// ---------------- readout (unchanged) ----------------
DEV void stage64(const unsigned short* __restrict__ src, int stride, int row0, int col0,
                 unsigned short (*lds)[80], int tid){
  int r = tid >> 3, cg = tid & 7;
  *(uint4*)(&lds[r][cg*8])      = *(const uint4*)(src + (size_t)(row0 + r)      * stride + col0 + cg*8);
  *(uint4*)(&lds[r + 32][cg*8]) = *(const uint4*)(src + (size_t)(row0 + r + 32) * stride + col0 + cg*8);
}
DEV void stage_tanh(const float* __restrict__ src, int stride, int row0, int col0,
                    unsigned short (*lds)[80], int tid){
  int r = tid >> 4, cg = tid & 15;
  #pragma unroll
  for (int rr = 0; rr < 4; rr++){
    int row = rr*16 + r;
    float4 v = *(const float4*)(src + (size_t)(row0 + row) * stride + col0 + cg*4);
    ushort4 o;
    o.x = f2bf(tanh_fast(v.x)); o.y = f2bf(tanh_fast(v.y));
    o.z = f2bf(tanh_fast(v.z)); o.w = f2bf(tanh_fast(v.w));
    *(ushort4*)(&lds[row][cg*4]) = o;
  }
}
DEV void mfma_tile(const unsigned short (*As)[80], const unsigned short (*Bs)[80],
                   f32x4 acc[2][2], int wr, int wc, int fr, int fq){
  #pragma unroll
  for (int kk = 0; kk < 64; kk += 32){
    short8 a0 = *(const short8*)(&As[wr*32 + fr     ][kk + fq*8]);
    short8 a1 = *(const short8*)(&As[wr*32 + 16 + fr][kk + fq*8]);
    short8 b0 = *(const short8*)(&Bs[wc*32 + fr     ][kk + fq*8]);
    short8 b1 = *(const short8*)(&Bs[wc*32 + 16 + fr][kk + fq*8]);
    acc[0][0] = __builtin_amdgcn_mfma_f32_16x16x32_bf16(a0, b0, acc[0][0], 0, 0, 0);
    acc[0][1] = __builtin_amdgcn_mfma_f32_16x16x32_bf16(a0, b1, acc[0][1], 0, 0, 0);
    acc[1][0] = __builtin_amdgcn_mfma_f32_16x16x32_bf16(a1, b0, acc[1][0], 0, 0, 0);
    acc[1][1] = __builtin_amdgcn_mfma_f32_16x16x32_bf16(a1, b1, acc[1][1], 0, 0, 0);
  }
}

__global__ __launch_bounds__(256) void k3a(const float* __restrict__ zc,
                                           const unsigned short* __restrict__ Wl1T,
                                           const float* __restrict__ bl1,
                                           unsigned short* __restrict__ rel){
  __shared__ __align__(16) unsigned short As[64][80], Bs[64][80];
  int tid = threadIdx.x, lane = tid & 63, wid = tid >> 6;
  int wr = wid >> 1, wc = wid & 1, fr = lane & 15, fq = lane >> 4;
  int m0 = blockIdx.x*64, n0 = blockIdx.y*64;
  f32x4 acc[2][2];
  #pragma unroll
  for (int m = 0; m < 2; m++)
    #pragma unroll
    for (int n = 0; n < 2; n++) acc[m][n] = (f32x4){0.f,0.f,0.f,0.f};
  for (int kc = 0; kc < H; kc += 64){
    __syncthreads();
    stage_tanh(zc,  H, m0, kc, As, tid);
    stage64(Wl1T,   H, n0, kc, Bs, tid);
    __syncthreads();
    mfma_tile(As, Bs, acc, wr, wc, fr, fq);
  }
  #pragma unroll
  for (int m = 0; m < 2; m++)
    #pragma unroll
    for (int n = 0; n < 2; n++)
      #pragma unroll
      for (int r = 0; r < 4; r++){
        int row = m0 + wr*32 + m*16 + fq*4 + r;
        int col = n0 + wc*32 + n*16 + fr;
        float v = acc[m][n][r] + bl1[col];
        rel[(size_t)row * H + col] = f2bf(fmaxf(v, 0.f));
      }
}

__global__ __launch_bounds__(256) void k3b(const unsigned short* __restrict__ rel,
                                           const unsigned short* __restrict__ Wl2T,
                                           const float* __restrict__ bl2,
                                           float* __restrict__ outc){
  __shared__ __align__(16) unsigned short As[64][80], Bs[64][80];
  int tid = threadIdx.x, lane = tid & 63, wid = tid >> 6;
  int wr = wid >> 1, wc = wid & 1, fr = lane & 15, fq = lane >> 4;
  int m0 = blockIdx.x*64;
  f32x4 acc[2][2];
  #pragma unroll
  for (int m = 0; m < 2; m++)
    #pragma unroll
    for (int n = 0; n < 2; n++) acc[m][n] = (f32x4){0.f,0.f,0.f,0.f};
  for (int kc = 0; kc < H; kc += 64){
    __syncthreads();
    stage64(rel,  H, m0, kc, As, tid);
    stage64(Wl2T, H, 0,  kc, Bs, tid);
    __syncthreads();
    mfma_tile(As, Bs, acc, wr, wc, fr, fq);
  }
  #pragma unroll
  for (int m = 0; m < 2; m++)
    #pragma unroll
    for (int n = 0; n < 2; n++)
      #pragma unroll
      for (int r = 0; r < 4; r++){
        int row = m0 + wr*32 + m*16 + fq*4 + r;
        int col = wc*32 + n*16 + fr;
        outc[(size_t)row * OUTD + col] = acc[m][n][r] + bl2[col];
      }
}

extern "C" void kernel_launch(void* const* d_in, const int* in_sizes, int n_in,
                              void* d_out, int out_size, void* d_ws, size_t ws_size,
                              hipStream_t stream){
  (void)in_sizes; (void)n_in; (void)out_size; (void)ws_size;
  const float* coeffs = (const float*)d_in[0];
  const float* times  = (const float*)d_in[1];
  const float* dW     = (const float*)d_in[2];
  const float* W_init = (const float*)d_in[3];
  const float* b_init = (const float*)d_in[4];
  const float* Wf1 = (const float*)d_in[5];
  const float* bf1 = (const float*)d_in[6];
  const float* Wf2 = (const float*)d_in[7];
  const float* bf2 = (const float*)d_in[8];
  const float* Wg1 = (const float*)d_in[9];
  const float* bg1 = (const float*)d_in[10];
  const float* Wg2 = (const float*)d_in[11];
  const float* bg2 = (const float*)d_in[12];
  const float* Wl1 = (const float*)d_in[13];
  const float* bl1 = (const float*)d_in[14];
  const float* Wl2 = (const float*)d_in[15];
  const float* bl2 = (const float*)d_in[16];

  float* out = (float*)d_out;
  float* z   = out + (size_t)Bsz * T * OUTD;   // z region of d_out, (B,T,H)

  char* w = (char*)d_ws;
  auto carve = [&](size_t bytes) -> void* {
    void* p = (void*)w; w += (bytes + 255) & ~(size_t)255; return p;
  };
  unsigned short* W1T  = (unsigned short*)carve((size_t)H2 * H * 2);
  unsigned short* W2T  = (unsigned short*)carve((size_t)H2 * H * 2);
  unsigned short* Wl1T = (unsigned short*)carve((size_t)H * H * 2);
  unsigned short* Wl2T = (unsigned short*)carve((size_t)OUTD * H * 2);
  unsigned short* rel  = (unsigned short*)carve((size_t)CROWS * H * 2);
  unsigned short* ygk  = (unsigned short*)carve((size_t)Bsz * H * 2);   // [16][1024][32]
  unsigned short* uk   = (unsigned short*)carve((size_t)Bsz * H2 * 2);  // [32][1024][32]
  unsigned*       cnts = (unsigned*)carve(16 * 32 * sizeof(unsigned));

  k_zero<<<dim3(2), 256, 0, stream>>>(cnts);
  k_prep<<<dim3(16, 16, 6), dim3(32, 8), 0, stream>>>(Wf1, Wg1, Wf2, Wg2, Wl1, Wl2,
                                                      W1T, W2T, Wl1T, Wl2T);
  k_scan<<<dim3(256), 512, 0, stream>>>(coeffs, times, dW, W_init, b_init,
                                        W1T, W2T, bf1, bg1, bf2, bg2,
                                        ygk, uk, z, cnts);
  for (int c = 0; c < NCHUNK; c++){
    k3a<<<dim3(CROWS / 64, 8), 256, 0, stream>>>(z + (size_t)c * CROWS * H, Wl1T, bl1, rel);
    k3b<<<dim3(CROWS / 64, 1), 256, 0, stream>>>(rel, Wl2T, bl2, out + (size_t)c * CROWS * OUTD);
  }
}

// Round 7
// 1140.311 us; speedup vs baseline: 5.4177x; 1.0362x over previous
//
#include <hip/hip_runtime.h>
#include <hip/hip_bf16.h>
#include <math.h>

#define DEV __device__ __forceinline__

typedef __attribute__((ext_vector_type(8))) short short8;
typedef __attribute__((ext_vector_type(4))) float f32x4;
typedef __attribute__((ext_vector_type(4))) unsigned int u32x4;

static constexpr int Bsz  = 1024;
static constexpr int T    = 100;
static constexpr int TM1  = 99;
static constexpr int H    = 512;
static constexpr int OUTD = 64;
static constexpr int H2   = 1024;
static constexpr int BT   = Bsz * T;        // 102400

DEV unsigned short f2bf(float f){
  unsigned int u = __float_as_uint(f);
  u += 0x7fffu + ((u >> 16) & 1u);          // round-to-nearest-even
  return (unsigned short)(u >> 16);
}
DEV unsigned pack2(float lo, float hi){
  return (unsigned)f2bf(lo) | ((unsigned)f2bf(hi) << 16);
}
DEV float tanh_fast(float x){
  x = fminf(fmaxf(x, -15.f), 15.f);
  float e = __expf(2.f * x);
  return (e - 1.f) / (e + 1.f);
}

// coherent (agent-scope, L3-backed) data path
#define AISSUE(dst, p) asm volatile("global_load_dwordx4 %0, %1, off sc0 sc1" : "=&v"(dst) : "v"(p) : "memory")
#define PLOAD(dst, p)  asm volatile("global_load_dword %0, %1, off"          : "=&v"(dst) : "v"(p) : "memory")
#define SC_STORE(p, v) asm volatile("global_store_dword %0, %1, off sc0 sc1" :: "v"(p), "v"(v) : "memory")
#define VWAIT(n)       asm volatile("s_waitcnt vmcnt(" #n ")" ::: "memory"); __builtin_amdgcn_sched_barrier(0)

// fence-free 16-block group barrier; callers drain their sc-stores (counted vmcnt) first
DEV void gbar(unsigned* cnt, unsigned target){
  __syncthreads();
  if (threadIdx.x == 0){
    __hip_atomic_fetch_add(cnt, 1u, __ATOMIC_RELAXED, __HIP_MEMORY_SCOPE_AGENT);
    while (__hip_atomic_load(cnt, __ATOMIC_RELAXED, __HIP_MEMORY_SCOPE_AGENT) < target)
      __builtin_amdgcn_s_sleep(1);
  }
  __syncthreads();
}

// ---------------- weight prep ----------------
// fmt 0: scan weights -> [col][k] bf16 with k sigma-permuted within 32-blocks
// fmt 1: Wl1 -> frag-major global: unit=(kc*512+col)*4+fq (16B units of 8 k-elems)
// fmt 2: Wl2 -> frag-major global: unit=(kc*64+col)*4+fq
__global__ __launch_bounds__(256) void k_prep(const float* __restrict__ Wf1, const float* __restrict__ Wg1,
                                              const float* __restrict__ Wf2, const float* __restrict__ Wg2,
                                              const float* __restrict__ Wl1, const float* __restrict__ Wl2,
                                              unsigned short* __restrict__ W1T, unsigned short* __restrict__ W2T,
                                              unsigned short* __restrict__ Wl1F, unsigned short* __restrict__ Wl2F){
  __shared__ float tl[32][33];
  const float* src; unsigned short* dst; int N; int fmt;
  switch (blockIdx.z){
    case 0: src = Wf1; dst = W1T;             N = 512; fmt = 0; break;
    case 1: src = Wg1; dst = W1T + 512*512;   N = 512; fmt = 0; break;
    case 2: src = Wf2; dst = W2T;             N = 512; fmt = 0; break;
    case 3: src = Wg2; dst = W2T + 512*512;   N = 512; fmt = 0; break;
    case 4: src = Wl1; dst = Wl1F;            N = 512; fmt = 1; break;
    default: src = Wl2; dst = Wl2F;           N = 64;  fmt = 2; break;
  }
  int k0 = blockIdx.x*32, n0 = blockIdx.y*32;
  if (n0 >= N) return;
  int tx = threadIdx.x, ty = threadIdx.y;     // block (32,8)
  #pragma unroll
  for (int r = 0; r < 4; r++) tl[ty + r*8][tx] = src[(size_t)(k0 + ty + r*8) * N + n0 + tx];
  __syncthreads();
  if (fmt == 0){
    int kpos = k0 + ((tx & 15)*2 + (tx >> 4));
    #pragma unroll
    for (int r = 0; r < 4; r++) dst[(size_t)(n0 + ty + r*8) * 512 + kpos] = f2bf(tl[tx][ty + r*8]);
  } else {
    int k = k0 + tx;
    int Nc = (fmt == 1) ? 512 : 64;
    #pragma unroll
    for (int r = 0; r < 4; r++){
      int col = n0 + ty + r*8;
      size_t idx = (((size_t)(k >> 5)*Nc + col)*4 + ((k >> 3) & 3))*8 + (k & 7);
      dst[idx] = f2bf(tl[tx][ty + r*8]);
    }
  }
}

__global__ void k_zero(unsigned* __restrict__ cnts){
  cnts[threadIdx.x + blockIdx.x*256] = 0u;
}

// ---- phase1 K-step: B from registers wb[32], A 8-deep prefetch ----
#define KS1(K, W) \
  VWAIT(W); \
  { short8 a_ = *(short8*)&ap[(K)&7]; \
    p0 = __builtin_amdgcn_mfma_f32_16x16x32_bf16(a_, wb[(K)*2],   p0, 0,0,0); \
    p1 = __builtin_amdgcn_mfma_f32_16x16x32_bf16(a_, wb[(K)*2+1], p1, 0,0,0); } \
  if ((K) < 8) { AISSUE(ap[(K)&7], abase1 + (size_t)((K)+8)*65536); }

#define RUN16_P1 \
  AISSUE(ap[0], abase1);          AISSUE(ap[1], abase1+65536); \
  AISSUE(ap[2], abase1+131072);   AISSUE(ap[3], abase1+196608); \
  AISSUE(ap[4], abase1+262144);   AISSUE(ap[5], abase1+327680); \
  AISSUE(ap[6], abase1+393216);   AISSUE(ap[7], abase1+458752); \
  KS1( 0,7) KS1( 1,7) KS1( 2,7) KS1( 3,7) KS1( 4,7) KS1( 5,7) KS1( 6,7) KS1( 7,7) \
  KS1( 8,7) KS1( 9,6) KS1(10,5) KS1(11,4) KS1(12,3) KS1(13,2) KS1(14,1) KS1(15,0)

// ---- phase2 K-step: B from LDS W2s, A 8-deep prefetch ----
#define KS2(K, W) \
  VWAIT(W); \
  { short8 a_  = *(short8*)&ap[(K)&7]; \
    short8 b0_ = *(const short8*)(Wb2 + (K)*4096 + fr*64 + fq*16); \
    short8 b1_ = *(const short8*)(Wb2 + (K)*4096 + 1024 + fr*64 + fq*16); \
    q0 = __builtin_amdgcn_mfma_f32_16x16x32_bf16(a_, b0_, q0, 0,0,0); \
    q1 = __builtin_amdgcn_mfma_f32_16x16x32_bf16(a_, b1_, q1, 0,0,0); } \
  if ((K) < 8) { AISSUE(ap[(K)&7], abase2 + (size_t)((K)+8)*65536); }

#define RUN16_P2 \
  AISSUE(ap[0], abase2);          AISSUE(ap[1], abase2+65536); \
  AISSUE(ap[2], abase2+131072);   AISSUE(ap[3], abase2+196608); \
  AISSUE(ap[4], abase2+262144);   AISSUE(ap[5], abase2+327680); \
  AISSUE(ap[6], abase2+393216);   AISSUE(ap[7], abase2+458752); \
  KS2( 0,7) KS2( 1,7) KS2( 2,7) KS2( 3,7) KS2( 4,7) KS2( 5,7) KS2( 6,7) KS2( 7,7) \
  KS2( 8,7) KS2( 9,6) KS2(10,5) KS2(11,4) KS2(12,3) KS2(13,2) KS2(14,1) KS2(15,0)

// ---------------- persistent group-synced scan, v5 ----------------
__global__ __launch_bounds__(512, 1) void k_scan(
    const float* __restrict__ coeffs, const float* __restrict__ times,
    const float* __restrict__ dW,     const float* __restrict__ W_init,
    const float* __restrict__ b_init,
    const unsigned short* __restrict__ W1T, const unsigned short* __restrict__ W2T,
    const float* __restrict__ bf1, const float* __restrict__ bg1,
    const float* __restrict__ bf2, const float* __restrict__ bg2,
    unsigned short* __restrict__ ygk, unsigned short* __restrict__ uk,
    float* __restrict__ z, unsigned* __restrict__ cnts){
  __shared__ __align__(16) unsigned char W1s[65536];   // [16 kc][64 col][4 fq] x16B
  __shared__ __align__(16) unsigned char W2s[65536];
  __shared__ __align__(16) float cmb[64*68];
  __shared__ float tms[104];

  const int bid = blockIdx.x, mt = bid & 15, ns = bid >> 4;
  const int m0 = mt*64, n1 = ns*64, n2 = ns*32;
  const int tid = threadIdx.x, lane = tid & 63, w = tid >> 6;
  const int fr = lane & 15, fq = lane >> 4;
  const int band = w & 3, isg = w >> 2;
  unsigned* cnt = cnts + mt*32;
  unsigned ep = 0;

  // ---- stage weight slices into LDS (frag-major) ----
  #pragma unroll
  for (int i = 0; i < 8; i++){
    int u = i*512 + tid;                     // unit = (kc*64+cl)*4+fqi
    int fqi = u & 3, cl = (u >> 2) & 63, kc = u >> 8;
    *(uint4*)(W1s + (size_t)u*16) = *(const uint4*)(W1T + (size_t)(n1+cl)*512 + kc*32 + fqi*8);
    const unsigned short* s2 = (cl < 32) ? (W2T + (size_t)(n2+cl)*512)
                                         : (W2T + (size_t)262144 + (size_t)(n2+cl-32)*512);
    *(uint4*)(W2s + (size_t)u*16) = *(const uint4*)(s2 + kc*32 + fqi*8);
  }
  if (tid < 100) tms[tid] = times[tid];
  { int row = tid >> 3, c0 = (tid & 7)*8;
    const float* src = coeffs + (size_t)(m0+row)*(TM1*4*64) + c0;
    *(float4*)(&cmb[row*68 + c0])     = *(const float4*)src;
    *(float4*)(&cmb[row*68 + c0 + 4]) = *(const float4*)(src + 4);
  }
  __syncthreads();

  // ---- phase1 weights -> registers (32 x short8 = 128 VGPR, static idx) ----
  short8 wb[32];
  #pragma unroll
  for (int kc = 0; kc < 16; ++kc){
    wb[kc*2]   = *(const short8*)(W1s + kc*4096 + isg*2048 +        fr*64 + fq*16);
    wb[kc*2+1] = *(const short8*)(W1s + kc*4096 + isg*2048 + 1024 + fr*64 + fq*16);
  }

  // per-lane pointers
  char* ygkb = (char*)ygk;
  char* ukb  = (char*)uk;
  const char* abase1 = ygkb + ((size_t)(m0 + band*16 + fr))*64 + fq*16;
  const char* abase2 = ukb + (size_t)isg*1048576 + ((size_t)(m0 + band*16 + fr))*64 + fq*16;
  char* ust = ukb  + ((size_t)((ns*2+isg)*1024 + m0 + band*16 + fq*4))*64 + fr*4;
  char* yst = ygkb + ((size_t)(ns*1024        + m0 + band*16 + fq*4))*64 + fr*4;
  const unsigned char* Wb2 = W2s + isg*2048;
  const float* dwb = dW + (size_t)(m0 + band*16 + fq*4)*512 + n2 + fr;
  float*       zb  = z  + ((size_t)(m0 + band*16 + fq*4)*T)*512 + n2 + fr;

  // ---- init: y0 = x0 @ W_init + b_init (g-waves own y slice) ----
  float yv[2][4];
  if (isg){
    #pragma unroll
    for (int r = 0; r < 4; r++){
      int row = band*16 + fq*4 + r;
      float s0 = b_init[n2 + fr], s1 = b_init[n2 + 16 + fr];
      #pragma unroll 8
      for (int k = 0; k < 64; k++){
        float xv = cmb[row*68 + k];
        s0 += xv * W_init[(size_t)k*512 + n2 + fr];
        s1 += xv * W_init[(size_t)k*512 + n2 + 16 + fr];
      }
      yv[0][r] = s0; yv[1][r] = s1;
      unsigned pv = pack2(s0, s1);
      SC_STORE(yst + r*64, pv);
      zb[(size_t)r*T*512]      = s0;
      zb[(size_t)r*T*512 + 16] = s1;
    }
    VWAIT(8);                                 // 4 y-sc complete; z may linger
  }
  ++ep; gbar(cnt, ep*16);

  // bias preloads
  const float b1v0 = ((n1 + isg*32 +      fr) < 512) ? bf1[n1 + isg*32 + fr]      : bg1[n1 + isg*32 + fr - 512];
  const float b1v1 = ((n1 + isg*32 + 16 + fr) < 512) ? bf1[n1 + isg*32 + 16 + fr] : bg1[n1 + isg*32 + 16 + fr - 512];
  const float b2v0 = isg ? bg2[n2 + fr]      : bf2[n2 + fr];
  const float b2v1 = isg ? bg2[n2 + 16 + fr] : bf2[n2 + 16 + fr];

  for (int t = 0; t < TM1; t++){
    float dv[8];
    // ===== phase 1: u = tanh(y @ W1 + b1); dW prefetch under barrier1 =====
    {
      f32x4 p0 = {0.f,0.f,0.f,0.f}, p1 = {0.f,0.f,0.f,0.f};
      u32x4 ap[8];
      RUN16_P1;
      #pragma unroll
      for (int r = 0; r < 4; r++){
        unsigned pv = pack2(tanh_fast(p0[r] + b1v0), tanh_fast(p1[r] + b1v1));
        SC_STORE(ust + r*64, pv);
      }
      if (isg){
        const char* dp = (const char*)(dwb + (size_t)t*524288);
        PLOAD(dv[0], dp + 0);    PLOAD(dv[1], dp + 64);
        PLOAD(dv[2], dp + 2048); PLOAD(dv[3], dp + 2048+64);
        PLOAD(dv[4], dp + 4096); PLOAD(dv[5], dp + 4096+64);
        PLOAD(dv[6], dp + 6144); PLOAD(dv[7], dp + 6144+64);
        VWAIT(8);                             // 4 u-sc complete; dW in flight
      } else {
        VWAIT(0);
      }
    }
    ++ep; gbar(cnt, ep*16);

    // ===== phase 2: f-waves u_f@Wf2, g-waves u_g@Wg2 + combine + y update =====
    {
      f32x4 q0 = {0.f,0.f,0.f,0.f}, q1 = {0.f,0.f,0.f,0.f};
      u32x4 ap[8];
      RUN16_P2;
      if (!isg){
        #pragma unroll
        for (int r = 0; r < 4; r++){
          int row = band*16 + fq*4 + r;
          cmb[row*68 + fr]      = q0[r] + b2v0;
          cmb[row*68 + 16 + fr] = q1[r] + b2v1;
        }
      }
      __syncthreads();
      if (isg){
        float h  = tms[t+1] - tms[t];
        float sq = sqrtf(h);
        #pragma unroll
        for (int r = 0; r < 4; r++){
          int row = band*16 + fq*4 + r;
          float f0 = cmb[row*68 + fr],        f1 = cmb[row*68 + 16 + fr];
          float g0 = tanh_fast(q0[r] + b2v0), g1 = tanh_fast(q1[r] + b2v1);
          float y0n = yv[0][r] + f0*h + g0*(sq*dv[r*2]);
          float y1n = yv[1][r] + f1*h + g1*(sq*dv[r*2+1]);
          yv[0][r] = y0n; yv[1][r] = y1n;
          unsigned pv = pack2(y0n, y1n);
          SC_STORE(yst + r*64, pv);
          zb[(size_t)r*T*512 + (size_t)(t+1)*512]      = y0n;
          zb[(size_t)r*T*512 + (size_t)(t+1)*512 + 16] = y1n;
        }
        VWAIT(8);                             // 4 y-sc complete; z may linger
      }
    }
    if (t < TM1-1){ ++ep; gbar(cnt, ep*16); }
  }
}

// ---------------- fused readout: out = relu(tanh(z)@Wl1+bl1)@Wl2+bl2 ----------------
// grid 1600 x 512 thr. Per block: 64 rows of BT. zt/relF frag-major LDS.
__global__ __launch_bounds__(512, 1) void k_read(
    const float* __restrict__ z, const unsigned short* __restrict__ Wl1F,
    const float* __restrict__ bl1, const unsigned short* __restrict__ Wl2F,
    const float* __restrict__ bl2, float* __restrict__ out){
  __shared__ __align__(16) unsigned char zt[65536];    // tanh(z) frag / f32 stage reuse
  __shared__ __align__(16) unsigned char relF[65536];  // rel frag-major
  const int tid = threadIdx.x, lane = tid & 63, w = tid >> 6;
  const int fr = lane & 15, fq = lane >> 4;
  const size_t rr0 = (size_t)blockIdx.x * 64;
  const int cw = w * 64;                               // GEMM1 col range of this wave

  // ---- stage: tanh(z) -> zt frag-major [kc][row][fq] ----
  { int row = tid >> 3, c0 = (tid & 7) * 64;
    const float* zr = z + (rr0 + row) * 512 + c0;
    #pragma unroll
    for (int j = 0; j < 2; ++j){
      int kc = (c0 >> 5) + j;
      #pragma unroll
      for (int f = 0; f < 4; ++f){
        float4 v0 = *(const float4*)(zr + j*32 + f*8);
        float4 v1 = *(const float4*)(zr + j*32 + f*8 + 4);
        unsigned d0 = pack2(tanh_fast(v0.x), tanh_fast(v0.y));
        unsigned d1 = pack2(tanh_fast(v0.z), tanh_fast(v0.w));
        unsigned d2 = pack2(tanh_fast(v1.x), tanh_fast(v1.y));
        unsigned d3 = pack2(tanh_fast(v1.z), tanh_fast(v1.w));
        uint4 pk = {d0, d1, d2, d3};
        *(uint4*)(zt + (size_t)((kc*64 + row)*4 + f)*16) = pk;
      }
    }
  }
  __syncthreads();

  // ---- GEMM1: wave w computes rows 64 x cols cw..cw+63, K=512 ----
  f32x4 acc[4][4];
  #pragma unroll
  for (int m = 0; m < 4; m++)
    #pragma unroll
    for (int c = 0; c < 4; c++) acc[m][c] = (f32x4){0.f,0.f,0.f,0.f};
  for (int kc = 0; kc < 16; ++kc){
    short8 a[4];
    #pragma unroll
    for (int m = 0; m < 4; m++)
      a[m] = *(const short8*)(zt + (size_t)((kc*64 + m*16 + fr)*4 + fq)*16);
    #pragma unroll
    for (int c = 0; c < 4; c++){
      short8 b = *(const short8*)(Wl1F + (((size_t)kc*512 + cw + c*16 + fr)*4 + fq)*8);
      #pragma unroll
      for (int m = 0; m < 4; m++)
        acc[m][c] = __builtin_amdgcn_mfma_f32_16x16x32_bf16(a[m], b, acc[m][c], 0, 0, 0);
    }
  }
  float bl1v[4];
  #pragma unroll
  for (int c = 0; c < 4; c++) bl1v[c] = bl1[cw + c*16 + fr];

  // ---- stage+pack relu -> relF frag-major, in 2 col-halves (zt reused as f32 stage) ----
  #pragma unroll
  for (int h = 0; h < 2; ++h){
    __syncthreads();
    if ((w >> 2) == h){                               // waves owning cols [256h, 256h+256)
      float* stg = (float*)zt;
      int cb = cw - h*256;
      #pragma unroll
      for (int m = 0; m < 4; m++)
        #pragma unroll
        for (int c = 0; c < 4; c++)
          #pragma unroll
          for (int r = 0; r < 4; r++)
            stg[(m*16 + fq*4 + r)*256 + cb + c*16 + fr] = fmaxf(acc[m][c][r] + bl1v[c], 0.f);
    }
    __syncthreads();
    { int row = tid >> 3, c8 = (tid & 7) * 32;
      const float* stg = (const float*)zt;
      int kc = h*8 + (tid & 7);
      #pragma unroll
      for (int f = 0; f < 4; ++f){
        const float* p = stg + row*256 + c8 + f*8;
        unsigned d0 = pack2(p[0], p[1]);
        unsigned d1 = pack2(p[2], p[3]);
        unsigned d2 = pack2(p[4], p[5]);
        unsigned d3 = pack2(p[6], p[7]);
        uint4 pk = {d0, d1, d2, d3};
        *(uint4*)(relF + (size_t)((kc*64 + row)*4 + f)*16) = pk;
      }
    }
  }
  __syncthreads();

  // ---- GEMM2: wave w -> rows (w&3)*16..+15, outcols (w>>2)*32..+31, K=512 ----
  f32x4 acc2[2];
  acc2[0] = (f32x4){0.f,0.f,0.f,0.f};
  acc2[1] = (f32x4){0.f,0.f,0.f,0.f};
  const int mt2 = w & 3, ocb = (w >> 2) * 32;
  for (int kc = 0; kc < 16; ++kc){
    short8 a = *(const short8*)(relF + (size_t)((kc*64 + mt2*16 + fr)*4 + fq)*16);
    #pragma unroll
    for (int j = 0; j < 2; j++){
      short8 b = *(const short8*)(Wl2F + (((size_t)(kc*64 + ocb + j*16 + fr))*4 + fq)*8);
      acc2[j] = __builtin_amdgcn_mfma_f32_16x16x32_bf16(a, b, acc2[j], 0, 0, 0);
    }
  }
  #pragma unroll
  for (int j = 0; j < 2; j++){
    #pragma unroll
    for (int r = 0; r < 4; r++){
      int row = mt2*16 + fq*4 + r;
      int oc  = ocb + j*16 + fr;
      out[(rr0 + row)*64 + oc] = acc2[j][r] + bl2[oc];
    }
  }
}

extern "C" void kernel_launch(void* const* d_in, const int* in_sizes, int n_in,
                              void* d_out, int out_size, void* d_ws, size_t ws_size,
                              hipStream_t stream){
  (void)in_sizes; (void)n_in; (void)out_size; (void)ws_size;
  const float* coeffs = (const float*)d_in[0];
  const float* times  = (const float*)d_in[1];
  const float* dW     = (const float*)d_in[2];
  const float* W_init = (const float*)d_in[3];
  const float* b_init = (const float*)d_in[4];
  const float* Wf1 = (const float*)d_in[5];
  const float* bf1 = (const float*)d_in[6];
  const float* Wf2 = (const float*)d_in[7];
  const float* bf2 = (const float*)d_in[8];
  const float* Wg1 = (const float*)d_in[9];
  const float* bg1 = (const float*)d_in[10];
  const float* Wg2 = (const float*)d_in[11];
  const float* bg2 = (const float*)d_in[12];
  const float* Wl1 = (const float*)d_in[13];
  const float* bl1 = (const float*)d_in[14];
  const float* Wl2 = (const float*)d_in[15];
  const float* bl2 = (const float*)d_in[16];

  float* out = (float*)d_out;
  float* z   = out + (size_t)Bsz * T * OUTD;   // z region of d_out, (B,T,H)

  char* wsp = (char*)d_ws;
  auto carve = [&](size_t bytes) -> void* {
    void* p = (void*)wsp; wsp += (bytes + 255) & ~(size_t)255; return p;
  };
  unsigned short* W1T  = (unsigned short*)carve((size_t)H2 * H * 2);
  unsigned short* W2T  = (unsigned short*)carve((size_t)H2 * H * 2);
  unsigned short* Wl1F = (unsigned short*)carve((size_t)H * H * 2);
  unsigned short* Wl2F = (unsigned short*)carve((size_t)OUTD * H * 2);
  unsigned short* ygk  = (unsigned short*)carve((size_t)Bsz * H * 2);   // [16][1024][32]
  unsigned short* uk   = (unsigned short*)carve((size_t)Bsz * H2 * 2);  // [32][1024][32]
  unsigned*       cnts = (unsigned*)carve(16 * 32 * sizeof(unsigned));

  k_zero<<<dim3(2), 256, 0, stream>>>(cnts);
  k_prep<<<dim3(16, 16, 6), dim3(32, 8), 0, stream>>>(Wf1, Wg1, Wf2, Wg2, Wl1, Wl2,
                                                      W1T, W2T, Wl1F, Wl2F);
  k_scan<<<dim3(256), 512, 0, stream>>>(coeffs, times, dW, W_init, b_init,
                                        W1T, W2T, bf1, bg1, bf2, bg2,
                                        ygk, uk, z, cnts);
  k_read<<<dim3(BT / 64), 512, 0, stream>>>(z, Wl1F, bl1, Wl2F, bl2, out);
}